// Round 14
// baseline (363.443 us; speedup 1.0000x reference)
//
#include <hip/hip_runtime.h>
#include <hip/hip_bf16.h>
#include <math.h>

typedef __attribute__((ext_vector_type(8))) short frag8;   // 8 bf16 (4 VGPRs)
typedef __attribute__((ext_vector_type(4))) float f32x4;

// ---------------- device helpers ----------------
__device__ __forceinline__ float gelu_exact(float x) {
    return 0.5f * x * (1.0f + erff(x * 0.70710678118654752f));
}
__device__ __forceinline__ float softplus_f(float x) {
    return (x > 20.0f) ? x : log1pf(expf(x));
}
__device__ __forceinline__ float sigmoid_f(float x) {
    return 1.0f / (1.0f + __expf(-x));
}
__device__ __forceinline__ unsigned short bf16bits(float x) {
    __hip_bfloat16 h = __float2bfloat16(x);
    return *(unsigned short*)&h;
}
__device__ __forceinline__ float bf2f(unsigned short u) {
    unsigned int v = ((unsigned int)u) << 16;
    return __builtin_bit_cast(float, v);
}
// sum over the 16 lanes of each DPP row-of-16 — VALU-pipe only
__device__ __forceinline__ float row_sum16(float x) {
    int t;
    t = __builtin_amdgcn_update_dpp(0, __builtin_bit_cast(int, x), 0x128, 0xf, 0xf, true); // row_ror:8
    x += __builtin_bit_cast(float, t);
    t = __builtin_amdgcn_update_dpp(0, __builtin_bit_cast(int, x), 0x124, 0xf, 0xf, true); // row_ror:4
    x += __builtin_bit_cast(float, t);
    t = __builtin_amdgcn_update_dpp(0, __builtin_bit_cast(int, x), 0x122, 0xf, 0xf, true); // row_ror:2
    x += __builtin_bit_cast(float, t);
    t = __builtin_amdgcn_update_dpp(0, __builtin_bit_cast(int, x), 0x121, 0xf, 0xf, true); // row_ror:1
    x += __builtin_bit_cast(float, t);
    return x;
}
// inclusive prefix sum over the full 64-lane wave (DPP, VALU-pipe only)
__device__ __forceinline__ float prefix_sum64(float x) {
    int t;
    t = __builtin_amdgcn_update_dpp(0, __builtin_bit_cast(int, x), 0x111, 0xf, 0xf, true); // row_shr:1
    x += __builtin_bit_cast(float, t);
    t = __builtin_amdgcn_update_dpp(0, __builtin_bit_cast(int, x), 0x112, 0xf, 0xf, true); // row_shr:2
    x += __builtin_bit_cast(float, t);
    t = __builtin_amdgcn_update_dpp(0, __builtin_bit_cast(int, x), 0x114, 0xf, 0xf, true); // row_shr:4
    x += __builtin_bit_cast(float, t);
    t = __builtin_amdgcn_update_dpp(0, __builtin_bit_cast(int, x), 0x118, 0xf, 0xf, true); // row_shr:8
    x += __builtin_bit_cast(float, t);
    t = __builtin_amdgcn_update_dpp(0, __builtin_bit_cast(int, x), 0x142, 0xa, 0xf, true); // row_bcast:15
    x += __builtin_bit_cast(float, t);
    t = __builtin_amdgcn_update_dpp(0, __builtin_bit_cast(int, x), 0x143, 0xc, 0xf, true); // row_bcast:31
    x += __builtin_bit_cast(float, t);
    return x;
}

// ---------------- fp32 -> bf16 weight conversion + Acoef setup + l2 zero --------
struct CvtArgs {
    const float* src[6];
    unsigned short* dst[6];
    int n4[6];
};
__global__ __launch_bounds__(256)
void cvt_all(CvtArgs a, int total4, const float* __restrict__ Alog,
             float* __restrict__ Ac, float* l2)
{
    int i = blockIdx.x * 256 + threadIdx.x;
    if (i >= total4) {
        int j = i - total4;
        if (j < 16384) Ac[j] = -__expf(Alog[j]);
        if (j == 0) *l2 = 0.0f;
        return;
    }
    int seg = 0;
    while (i >= a.n4[seg]) { i -= a.n4[seg]; seg++; }
    float4 v = reinterpret_cast<const float4*>(a.src[seg])[i];
    ushort4 o;
    o.x = bf16bits(v.x); o.y = bf16bits(v.y); o.z = bf16bits(v.z); o.w = bf16bits(v.w);
    reinterpret_cast<ushort4*>(a.dst[seg])[i] = o;
}

// ---------------- ipw GEMM (N=1024, K=256): u-half -> xzuT fp32 [b][d][t],
// ---------------- z-half -> silu(z) bf16 szT [b][d][t] ----------------
__global__ __launch_bounds__(256)
void gemm_ipw(const unsigned short* __restrict__ A,
              const unsigned short* __restrict__ W,
              float* __restrict__ xzuT,
              unsigned short* __restrict__ szT)
{
    __shared__ __align__(16) unsigned short As[64][40];
    __shared__ __align__(16) unsigned short Bs[64][40];

    const int tid = threadIdx.x;
    const int wid = tid >> 6, lane = tid & 63;
    const int wm = (wid >> 1) * 32, wn = (wid & 1) * 32;
    const int m0 = blockIdx.y * 64, n0 = blockIdx.x * 64;
    const int lrow = lane & 15, quad = lane >> 4;
    const int K = 256;

    const int sm = tid >> 2;
    const int sk = (tid & 3) * 8;

    f32x4 acc[2][2] = {};

    for (int k0 = 0; k0 < K; k0 += 32) {
        float4 av = *reinterpret_cast<const float4*>(A + (size_t)(m0 + sm) * K + k0 + sk);
        *reinterpret_cast<float4*>(&As[sm][sk]) = av;
        float4 bv = *reinterpret_cast<const float4*>(W + (size_t)(n0 + sm) * K + k0 + sk);
        *reinterpret_cast<float4*>(&Bs[sm][sk]) = bv;
        __syncthreads();

        frag8 a0 = *reinterpret_cast<const frag8*>(&As[wm + lrow][quad * 8]);
        frag8 a1 = *reinterpret_cast<const frag8*>(&As[wm + 16 + lrow][quad * 8]);
        frag8 b0 = *reinterpret_cast<const frag8*>(&Bs[wn + lrow][quad * 8]);
        frag8 b1 = *reinterpret_cast<const frag8*>(&Bs[wn + 16 + lrow][quad * 8]);

        acc[0][0] = __builtin_amdgcn_mfma_f32_16x16x32_bf16(a0, b0, acc[0][0], 0, 0, 0);
        acc[0][1] = __builtin_amdgcn_mfma_f32_16x16x32_bf16(a0, b1, acc[0][1], 0, 0, 0);
        acc[1][0] = __builtin_amdgcn_mfma_f32_16x16x32_bf16(a1, b0, acc[1][0], 0, 0, 0);
        acc[1][1] = __builtin_amdgcn_mfma_f32_16x16x32_bf16(a1, b1, acc[1][1], 0, 0, 0);
        __syncthreads();
    }

    const int bb = m0 >> 10;
    const int tb = m0 & 1023;
    #pragma unroll
    for (int mi = 0; mi < 2; mi++) {
        int t4 = tb + wm + mi * 16 + quad * 4;
        #pragma unroll
        for (int nj = 0; nj < 2; nj++) {
            int col = n0 + wn + nj * 16 + lrow;
            if (col < 512) {
                float4 o = { acc[mi][nj][0], acc[mi][nj][1], acc[mi][nj][2], acc[mi][nj][3] };
                *reinterpret_cast<float4*>(xzuT + ((size_t)(bb * 512 + col)) * 1024 + t4) = o;
            } else {
                int z = col - 512;
                ushort4 o;
                float v0 = acc[mi][nj][0], v1 = acc[mi][nj][1], v2 = acc[mi][nj][2], v3 = acc[mi][nj][3];
                o.x = bf16bits(v0 * sigmoid_f(v0));
                o.y = bf16bits(v1 * sigmoid_f(v1));
                o.z = bf16bits(v2 * sigmoid_f(v2));
                o.w = bf16bits(v3 * sigmoid_f(v3));
                *reinterpret_cast<ushort4*>(szT + ((size_t)(bb * 512 + z)) * 1024 + t4) = o;
            }
        }
    }
}

// ---------------- conv4+SiLU fused into xpw projection, K-split x4 --------------
__global__ __launch_bounds__(256)
void gemm_cat(const float* __restrict__ xzuT,
              const unsigned short* __restrict__ W,     // xpw: 48 x 512 bf16
              const float* __restrict__ cw, const float* __restrict__ cb,
              float* __restrict__ ucT,
              float* __restrict__ xp0, float* __restrict__ xp123)
{
    __shared__ __align__(16) unsigned short As[64][40];
    __shared__ __align__(16) unsigned short Bs[64][40];

    const int tid = threadIdx.x;
    const int wid = tid >> 6, lane = tid & 63;
    const int wm = (wid >> 1) * 32, wn = (wid & 1) * 32;
    const int kc = blockIdx.x;            // 0..3 (128-d chunk)
    const int m0 = blockIdx.y * 64;
    const int bb = m0 >> 10;
    const int tb = m0 & 1023;
    const int lrow = lane & 15, quad = lane >> 4;
    const int N = 48;

    const int sm = tid >> 2;
    const int sk = (tid & 3) * 8;

    f32x4 acc[2][2] = {};

    for (int k0 = 0; k0 < 128; k0 += 32) {
        #pragma unroll
        for (int p = 0; p < 2; p++) {
            int kk = (tid >> 4) + p * 16;
            int k  = kc * 128 + k0 + kk;
            int mq = tid & 15;
            int tg = tb + mq * 4;
            const float* rowp = xzuT + ((size_t)(bb * 512 + k)) * 1024;
            float4 cur = *reinterpret_cast<const float4*>(rowp + tg);
            float4 prev = {0.f, 0.f, 0.f, 0.f};
            if (tg != 0) prev = *reinterpret_cast<const float4*>(rowp + tg - 4);
            float4 cv = *reinterpret_cast<const float4*>(cw + k * 4);
            float cbv = cb[k];
            float o0 = cbv + cv.x*prev.y + cv.y*prev.z + cv.z*prev.w + cv.w*cur.x;
            float o1 = cbv + cv.x*prev.z + cv.y*prev.w + cv.z*cur.x  + cv.w*cur.y;
            float o2 = cbv + cv.x*prev.w + cv.y*cur.x  + cv.z*cur.y  + cv.w*cur.z;
            float o3 = cbv + cv.x*cur.x  + cv.y*cur.y  + cv.z*cur.z  + cv.w*cur.w;
            o0 *= sigmoid_f(o0); o1 *= sigmoid_f(o1);
            o2 *= sigmoid_f(o2); o3 *= sigmoid_f(o3);
            float4 uo = { o0, o1, o2, o3 };
            *reinterpret_cast<float4*>(ucT + ((size_t)(bb * 512 + k)) * 1024 + tg) = uo;
            As[mq * 4 + 0][kk] = bf16bits(o0);
            As[mq * 4 + 1][kk] = bf16bits(o1);
            As[mq * 4 + 2][kk] = bf16bits(o2);
            As[mq * 4 + 3][kk] = bf16bits(o3);
        }
        float4 bv = {0.f, 0.f, 0.f, 0.f};
        if (sm < N) bv = *reinterpret_cast<const float4*>(W + (size_t)sm * 512 + kc * 128 + k0 + sk);
        *reinterpret_cast<float4*>(&Bs[sm][sk]) = bv;
        __syncthreads();

        frag8 a0 = *reinterpret_cast<const frag8*>(&As[wm + lrow][quad * 8]);
        frag8 a1 = *reinterpret_cast<const frag8*>(&As[wm + 16 + lrow][quad * 8]);
        frag8 b0 = *reinterpret_cast<const frag8*>(&Bs[wn + lrow][quad * 8]);
        frag8 b1 = *reinterpret_cast<const frag8*>(&Bs[wn + 16 + lrow][quad * 8]);

        acc[0][0] = __builtin_amdgcn_mfma_f32_16x16x32_bf16(a0, b0, acc[0][0], 0, 0, 0);
        acc[0][1] = __builtin_amdgcn_mfma_f32_16x16x32_bf16(a0, b1, acc[0][1], 0, 0, 0);
        acc[1][0] = __builtin_amdgcn_mfma_f32_16x16x32_bf16(a1, b0, acc[1][0], 0, 0, 0);
        acc[1][1] = __builtin_amdgcn_mfma_f32_16x16x32_bf16(a1, b1, acc[1][1], 0, 0, 0);
        __syncthreads();
    }

    float* C = (kc == 0) ? xp0 : (xp123 + (size_t)(kc - 1) * 4096 * 48);
    #pragma unroll
    for (int mi = 0; mi < 2; mi++) {
        #pragma unroll
        for (int nj = 0; nj < 2; nj++) {
            int col = wn + nj * 16 + lrow;
            if (col >= N) continue;
            #pragma unroll
            for (int r = 0; r < 4; r++) {
                int row = m0 + wm + mi * 16 + quad * 4 + r;
                C[(size_t)row * N + col] = acc[mi][nj][r];
            }
        }
    }
}

// ---------------- full-row GEMM (N=256), 512 threads / 8 waves ------------------
// Af != nullptr: stage A from fp32 (converting); else from bf16 A.
__global__ __launch_bounds__(512)
void rowgemm(const unsigned short* __restrict__ A,
             const float* __restrict__ Af,
             const unsigned short* __restrict__ W,
             const float* __restrict__ bias,
             const float* res,
             const float* g1, const float* b1, int gelu1,
             const float* g2, const float* b2,
             float* outF, unsigned short* outB, float* l2out,
             const unsigned short* clsW, const float* clsB, float* clsOut,
             int K)
{
    __shared__ __align__(16) unsigned short As[16][40];
    __shared__ __align__(16) unsigned short Bs[256][40];
    __shared__ float red[8][16][2];
    __shared__ float sq[16];
    __shared__ __align__(16) unsigned short hb[16][264];

    const int tid = threadIdx.x;
    const int w = tid >> 6, lane = tid & 63;
    const int lrow = lane & 15, quad = lane >> 4;
    const int m0 = blockIdx.x * 16;

    f32x4 acc[2] = {};

    for (int k0 = 0; k0 < K; k0 += 32) {
        if (tid < 64) {
            int r_ = tid >> 2, c8 = (tid & 3) * 8;
            if (Af) {
                float4 v0 = *reinterpret_cast<const float4*>(Af + (size_t)(m0 + r_) * K + k0 + c8);
                float4 v1 = *reinterpret_cast<const float4*>(Af + (size_t)(m0 + r_) * K + k0 + c8 + 4);
                unsigned short* dst = &As[r_][c8];
                dst[0] = bf16bits(v0.x); dst[1] = bf16bits(v0.y);
                dst[2] = bf16bits(v0.z); dst[3] = bf16bits(v0.w);
                dst[4] = bf16bits(v1.x); dst[5] = bf16bits(v1.y);
                dst[6] = bf16bits(v1.z); dst[7] = bf16bits(v1.w);
            } else {
                float4 av = *reinterpret_cast<const float4*>(A + (size_t)(m0 + r_) * K + k0 + c8);
                *reinterpret_cast<float4*>(&As[r_][c8]) = av;
            }
        }
        #pragma unroll
        for (int i = 0; i < 2; i++) {
            int n = (tid >> 2) + i * 128;
            float4 bv = *reinterpret_cast<const float4*>(W + (size_t)n * K + k0 + (tid & 3) * 8);
            *reinterpret_cast<float4*>(&Bs[n][(tid & 3) * 8]) = bv;
        }
        __syncthreads();
        frag8 a = *reinterpret_cast<const frag8*>(&As[lrow][quad * 8]);
        #pragma unroll
        for (int nj = 0; nj < 2; nj++) {
            frag8 b = *reinterpret_cast<const frag8*>(&Bs[w * 32 + nj * 16 + lrow][quad * 8]);
            acc[nj] = __builtin_amdgcn_mfma_f32_16x16x32_bf16(a, b, acc[nj], 0, 0, 0);
        }
        __syncthreads();
    }

    float v[2][4];
    #pragma unroll
    for (int nj = 0; nj < 2; nj++) {
        int col = w * 32 + nj * 16 + lrow;
        #pragma unroll
        for (int r = 0; r < 4; r++) {
            int row = m0 + quad * 4 + r;
            float t = acc[nj][r];
            if (bias) t += bias[col];
            if (res) t += res[(size_t)row * 256 + col];
            v[nj][r] = t;
        }
    }

    if (g1) {
        #pragma unroll
        for (int r = 0; r < 4; r++) {
            float s1 = v[0][r] + v[1][r];
            float s2 = v[0][r]*v[0][r] + v[1][r]*v[1][r];
            s1 = row_sum16(s1); s2 = row_sum16(s2);
            if (lrow == 0) { red[w][quad * 4 + r][0] = s1; red[w][quad * 4 + r][1] = s2; }
        }
        __syncthreads();
        #pragma unroll
        for (int r = 0; r < 4; r++) {
            int rr = quad * 4 + r;
            float t1 = 0.f, t2 = 0.f;
            #pragma unroll
            for (int ww = 0; ww < 8; ww++) { t1 += red[ww][rr][0]; t2 += red[ww][rr][1]; }
            float mu = t1 * (1.0f / 256.0f);
            float var = t2 * (1.0f / 256.0f) - mu * mu;
            float rstd = rsqrtf(var + 1e-5f);
            #pragma unroll
            for (int nj = 0; nj < 2; nj++) {
                int col = w * 32 + nj * 16 + lrow;
                float t = (v[nj][r] - mu) * rstd * g1[col] + b1[col];
                if (gelu1) t = gelu_exact(t);
                v[nj][r] = t;
            }
        }
        __syncthreads();
    } else if (gelu1) {
        #pragma unroll
        for (int nj = 0; nj < 2; nj++)
            #pragma unroll
            for (int r = 0; r < 4; r++)
                v[nj][r] = gelu_exact(v[nj][r]);
    }

    if (outF) {
        #pragma unroll
        for (int nj = 0; nj < 2; nj++) {
            int col = w * 32 + nj * 16 + lrow;
            #pragma unroll
            for (int r = 0; r < 4; r++)
                outF[(size_t)(m0 + quad * 4 + r) * 256 + col] = v[nj][r];
        }
    }

    if (l2out) {
        #pragma unroll
        for (int r = 0; r < 4; r++) {
            float s2 = v[0][r]*v[0][r] + v[1][r]*v[1][r];
            s2 = row_sum16(s2);
            if (lrow == 0) red[w][quad * 4 + r][0] = s2;
        }
        __syncthreads();
        if (tid < 16) {
            float t = 0.f;
            #pragma unroll
            for (int ww = 0; ww < 8; ww++) t += red[ww][tid][0];
            sq[tid] = sqrtf(t);
        }
        __syncthreads();
        if (tid == 0) {
            float a = 0.f;
            #pragma unroll
            for (int i = 0; i < 16; i++) a += sq[i];
            atomicAdd(l2out, a * (0.01f / 4096.0f));
        }
    }

    if (g2) {
        __syncthreads();
        #pragma unroll
        for (int r = 0; r < 4; r++) {
            float s1 = v[0][r] + v[1][r];
            float s2 = v[0][r]*v[0][r] + v[1][r]*v[1][r];
            s1 = row_sum16(s1); s2 = row_sum16(s2);
            if (lrow == 0) { red[w][quad * 4 + r][0] = s1; red[w][quad * 4 + r][1] = s2; }
        }
        __syncthreads();
        #pragma unroll
        for (int r = 0; r < 4; r++) {
            int rr = quad * 4 + r;
            float t1 = 0.f, t2 = 0.f;
            #pragma unroll
            for (int ww = 0; ww < 8; ww++) { t1 += red[ww][rr][0]; t2 += red[ww][rr][1]; }
            float mu = t1 * (1.0f / 256.0f);
            float var = t2 * (1.0f / 256.0f) - mu * mu;
            float rstd = rsqrtf(var + 1e-5f);
            #pragma unroll
            for (int nj = 0; nj < 2; nj++) {
                int col = w * 32 + nj * 16 + lrow;
                outB[(size_t)(m0 + rr) * 256 + col] = bf16bits((v[nj][r] - mu) * rstd * g2[col] + b2[col]);
            }
        }
    } else if (outB) {
        #pragma unroll
        for (int nj = 0; nj < 2; nj++) {
            int col = w * 32 + nj * 16 + lrow;
            #pragma unroll
            for (int r = 0; r < 4; r++)
                outB[(size_t)(m0 + quad * 4 + r) * 256 + col] = bf16bits(v[nj][r]);
        }
    }

    // ---- fused cls GEMM: logits(16 x 128) = v(16 x 256) @ clsW(128 x 256)^T ----
    if (clsW) {
        #pragma unroll
        for (int nj = 0; nj < 2; nj++) {
            int col = w * 32 + nj * 16 + lrow;
            #pragma unroll
            for (int r = 0; r < 4; r++)
                hb[quad * 4 + r][col] = bf16bits(v[nj][r]);
        }
        __syncthreads();
        f32x4 cacc = {};
        #pragma unroll
        for (int k0 = 0; k0 < 256; k0 += 32) {
            frag8 a = *reinterpret_cast<const frag8*>(&hb[lrow][k0 + quad * 8]);
            frag8 b = *reinterpret_cast<const frag8*>(clsW + (size_t)(w * 16 + lrow) * 256 + k0 + quad * 8);
            cacc = __builtin_amdgcn_mfma_f32_16x16x32_bf16(a, b, cacc, 0, 0, 0);
        }
        int col = w * 16 + lrow;
        float cb = clsB[col];
        #pragma unroll
        for (int r = 0; r < 4; r++)
            clsOut[(size_t)(m0 + quad * 4 + r) * 128 + col] = cacc[r] + cb;
    }
}

// ---------------- dt proj + softplus -> dltT ; fused B/C transpose --------------
__global__ __launch_bounds__(256)
void dtbc(const float* __restrict__ xp0, const float* __restrict__ xp123,
          const float* __restrict__ dtw,
          const float* __restrict__ dtb, float* __restrict__ dltT,
          float* __restrict__ BT, float* __restrict__ CT)
{
    __shared__ float xd[64][17];
    __shared__ float wS[64][16];
    __shared__ float bS[64];
    const size_t S = (size_t)4096 * 48;
    const int bx = blockIdx.x;
    const int b = bx >> 7;
    const int tt = (bx >> 3) & 15;
    const int dg = bx & 7;
    const int tid = threadIdx.x;
    const int t0 = tt * 64, d0 = dg * 64;

    for (int i = tid; i < 64 * 16; i += 256) {
        int t = i >> 4, k = i & 15;
        size_t off = ((size_t)(b * 1024 + t0 + t)) * 48 + k;
        xd[t][k] = xp0[off] + xp123[off] + xp123[S + off] + xp123[2 * S + off];
    }
    for (int i = tid; i < 64 * 16; i += 256) {
        int dl = i >> 4, k = i & 15;
        wS[dl][k] = dtw[(d0 + dl) * 16 + k];
    }
    if (tid < 64) bS[tid] = dtb[d0 + tid];
    __syncthreads();

    const int tl = tid & 63, w = tid >> 6;
    #pragma unroll 4
    for (int di = 0; di < 16; di++) {
        int dl = w * 16 + di;
        float acc = bS[dl];
        #pragma unroll
        for (int k = 0; k < 16; k++) acc += xd[tl][k] * wS[dl][k];
        dltT[((size_t)(b * 512 + d0 + dl)) * 1024 + t0 + tl] = softplus_f(acc);
    }

    {
        int c = tid >> 6;
        int t = tid & 63;
        int col = dg * 4 + c;
        size_t off = ((size_t)(b * 1024 + t0 + t)) * 48 + 16 + col;
        float v = xp0[off] + xp123[off] + xp123[S + off] + xp123[2 * S + off];
        if (col < 16) BT[((size_t)(b * 16 + col)) * 1024 + t0 + t] = v;
        else          CT[((size_t)(b * 16 + col - 16)) * 1024 + t0 + t] = v;
    }
}

// ---------------- chunked selective scan (1 barrier, 2-deep prefetch) -----------
__global__ __launch_bounds__(1024)
void scan_chunked(const float* __restrict__ dltT, const float* __restrict__ ucT,
                  const float* __restrict__ BT, const float* __restrict__ CT,
                  const unsigned short* __restrict__ szT,
                  const float* __restrict__ Ac,
                  const float* __restrict__ Dp,
                  unsigned short* __restrict__ y)
{
    __shared__ float aprod_s[16][64];
    __shared__ float sfin_s[16][64];
    __shared__ float sin_w[16][64];
    __shared__ __align__(16) float ylocal[16][64][4];

    const int j = blockIdx.x;
    const int bid = (j & 7) * 64 + (j >> 3);     // XCD swizzle
    const int b = bid >> 7;
    const int d0 = (bid & 127) * 4;
    const int w = threadIdx.x >> 6;
    const int lane = threadIdx.x & 63;
    const int dsub = lane >> 4, s = lane & 15;
    const int d = d0 + dsub;

    const float Acoef = Ac[d * 16 + s];

    const float4* dp = reinterpret_cast<const float4*>(dltT + ((size_t)(b * 512 + d)) * 1024 + w * 64);
    const float4* up = reinterpret_cast<const float4*>(ucT  + ((size_t)(b * 512 + d)) * 1024 + w * 64);
    const float4* Bp = reinterpret_cast<const float4*>(BT + ((size_t)(b * 16 + s)) * 1024 + w * 64);
    const float4* Cp = reinterpret_cast<const float4*>(CT + ((size_t)(b * 16 + s)) * 1024 + w * 64);

    // ---- Phase A: local scan, 2-deep prefetch, ylocal via register select ----
    float st = 0.0f, ap = 1.0f;
    float yreg[4] = {0.f, 0.f, 0.f, 0.f};
    float4 c0d = dp[0], c0u = up[0], c0B = Bp[0], c0C = Cp[0];
    float4 c1d = dp[1], c1u = up[1], c1B = Bp[1], c1C = Cp[1];
    #pragma unroll
    for (int q = 0; q < 16; q++) {
        float4 nd, nu, nB, nC;
        if (q < 14) { nd = dp[q + 2]; nu = up[q + 2]; nB = Bp[q + 2]; nC = Cp[q + 2]; }
        const float* dtp = (const float*)&c0d;
        const float* utp = (const float*)&c0u;
        const float* Btp = (const float*)&c0B;
        const float* Ctp = (const float*)&c0C;
        #pragma unroll
        for (int jj = 0; jj < 4; jj++) {
            const int tl = q * 4 + jj;
            float dA = __expf(dtp[jj] * Acoef);
            st = st * dA + dtp[jj] * utp[jj] * Btp[jj];
            ap *= dA;
            float part = row_sum16(st * Ctp[jj]);
            if (s == (tl & 15)) yreg[tl >> 4] = part;
        }
        c0d = c1d; c0u = c1u; c0B = c1B; c0C = c1C;
        c1d = nd; c1u = nu; c1B = nB; c1C = nC;
    }
    aprod_s[w][lane] = ap;
    sfin_s[w][lane] = st;
    #pragma unroll
    for (int r = 0; r < 4; r++)
        ylocal[w][r * 16 + s][dsub] = yreg[r];
    __syncthreads();                                 // the only barrier

    // ---- decentralized combine ----
    {
        float pre = 0.0f;
        #pragma unroll
        for (int c = 0; c < 15; c++) {
            float apc = aprod_s[c][lane];
            float sfc = sfin_s[c][lane];
            float cand = sfc + apc * pre;
            pre = (c < w) ? cand : pre;
        }
        sin_w[w][lane] = pre;
    }

    // ---- Phase C: lane = t; correction via prefix sums + epilogue ----
    const int t = w * 64 + lane;
    float cums[4];
    #pragma unroll
    for (int dd = 0; dd < 4; dd++)
        cums[dd] = dltT[((size_t)(b * 512 + d0 + dd)) * 1024 + t];
    #pragma unroll
    for (int dd = 0; dd < 4; dd++)
        cums[dd] = prefix_sum64(cums[dd]);

    float4 yl = *reinterpret_cast<const float4*>(&ylocal[w][lane][0]);
    float acc[4] = { yl.x, yl.y, yl.z, yl.w };

    #pragma unroll
    for (int sq = 0; sq < 4; sq++) {
        float Cs[4];
        #pragma unroll
        for (int jj = 0; jj < 4; jj++)
            Cs[jj] = CT[((size_t)(b * 16 + sq * 4 + jj)) * 1024 + t];
        #pragma unroll
        for (int dd = 0; dd < 4; dd++) {
            float4 sin4 = *reinterpret_cast<const float4*>(&sin_w[w][dd * 16 + sq * 4]);
            const float* sp = (const float*)&sin4;
            #pragma unroll
            for (int jj = 0; jj < 4; jj++) {
                float ac = Ac[(d0 + dd) * 16 + sq * 4 + jj];
                acc[dd] += sp[jj] * Cs[jj] * __expf(ac * cums[dd]);
            }
        }
    }

    const size_t row = (size_t)b * 1024 + t;
    #pragma unroll
    for (int dd = 0; dd < 4; dd++) {
        float ut = ucT[((size_t)(b * 512 + d0 + dd)) * 1024 + t];
        float sz = bf2f(szT[((size_t)(b * 512 + d0 + dd)) * 1024 + t]);
        float yv = acc[dd] + ut * Dp[d0 + dd];
        y[row * 512 + d0 + dd] = bf16bits(yv * sz);
    }
}

// ---------------- launcher ----------------
extern "C" void kernel_launch(void* const* d_in, const int* in_sizes, int n_in,
                              void* d_out, int out_size, void* d_ws, size_t ws_size,
                              hipStream_t stream)
{
    const float* x      = (const float*)d_in[0];
    const float* in_b   = (const float*)d_in[2];
    const float* ln_g   = (const float*)d_in[3];
    const float* ln_b   = (const float*)d_in[4];
    const float* blk_ng  = (const float*)d_in[5];
    const float* blk_nb  = (const float*)d_in[6];
    const float* blk_cw  = (const float*)d_in[8];
    const float* blk_cb  = (const float*)d_in[9];
    const float* blk_dtw = (const float*)d_in[11];
    const float* blk_dtb = (const float*)d_in[12];
    const float* blk_Alog= (const float*)d_in[13];
    const float* blk_D   = (const float*)d_in[14];
    const float* op_b   = (const float*)d_in[17];
    const float* cls_b  = (const float*)d_in[19];
    float* out = (float*)d_out;

    const int BL = 4096;
    float* ws = (float*)d_ws;
    float* h0   = ws;                         // 1,048,576
    float* xzuT = h0 + 1048576;               // 2,097,152  [b][d][t] fp32 (u pre-conv)
    float* ucT  = xzuT + 2097152;             // 2,097,152  [b][d][t]
    float* xdbc = ucT + 2097152;              //   196,608  (xdbcp chunk 0)
    float* dltT = xdbc + 196608;              // 2,097,152  [b][d][t]
    float* BT   = dltT + 2097152;             //    65,536  [b][s][t]
    float* CT   = BT + 65536;                 //    65,536  [b][s][t]
    float* Ac   = CT + 65536;                 //    16,384
    unsigned short* szT = (unsigned short*)(Ac + 16384);  // 2,097,152 bf16 [b][d][t]
    unsigned short* wb  = szT + 2097152;      // 1,130,496
    unsigned short* hnb = wb + 1130496;       // 1,048,576
    unsigned short* ybb = hnb + 1048576;      // 2,097,152
    unsigned short* h0b = hnb;
    float* xp123 = (float*)ybb;               // xdbcp chunks 1..3 (dead-ybb alias)
    unsigned short* in_wb  = wb;
    unsigned short* ipw_b  = wb + 196608;
    unsigned short* xpw_b  = wb + 720896;
    unsigned short* opw_b  = wb + 770048;
    unsigned short* op_wb  = wb + 1032192;
    unsigned short* cls_wb = wb + 1097728;

    CvtArgs ca;
    ca.src[0] = (const float*)d_in[1];  ca.dst[0] = in_wb;  ca.n4[0] = 196608 / 4;
    ca.src[1] = (const float*)d_in[7];  ca.dst[1] = ipw_b;  ca.n4[1] = 524288 / 4;
    ca.src[2] = (const float*)d_in[10]; ca.dst[2] = xpw_b;  ca.n4[2] = 49152 / 4;
    ca.src[3] = (const float*)d_in[15]; ca.dst[3] = opw_b;  ca.n4[3] = 262144 / 4;
    ca.src[4] = (const float*)d_in[16]; ca.dst[4] = op_wb;  ca.n4[4] = 65536 / 4;
    ca.src[5] = (const float*)d_in[18]; ca.dst[5] = cls_wb; ca.n4[5] = 32768 / 4;
    int total4 = 1130496 / 4;
    int totalg = total4 + 16384;
    cvt_all<<<(totalg + 255) / 256, 256, 0, stream>>>(ca, total4, blk_Alog, Ac,
                                                      out + (size_t)BL * 128);

    // in_proj (A from fp32 x) + bias + LN + GELU -> h0 (fp32), + LN(layer0) -> hnb
    rowgemm<<<256, 512, 0, stream>>>(nullptr, x, in_wb, in_b, nullptr,
                                     ln_g, ln_b, 1,
                                     blk_ng, blk_nb,
                                     h0, hnb, nullptr,
                                     nullptr, nullptr, nullptr, 768);

    for (int l = 0; l < 2; l++) {
        const float* cw   = blk_cw  + (size_t)l * 512 * 4;
        const float* cb   = blk_cb  + l * 512;
        const float* dtw  = blk_dtw + (size_t)l * 512 * 16;
        const float* dtb  = blk_dtb + l * 512;
        const float* Dl   = blk_D   + l * 512;
        const unsigned short* ipwl = ipw_b + (size_t)l * 262144;
        const unsigned short* xpwl = xpw_b + (size_t)l * 24576;
        const unsigned short* opwl = opw_b + (size_t)l * 131072;

        // ipw GEMM: u -> xzuT fp32 [b][d][t]; z -> silu(z) bf16 szT [b][d][t]
        gemm_ipw<<<dim3(16, 64), 256, 0, stream>>>(hnb, ipwl, xzuT, szT);
        // fused conv + xpw projection (K-split x4): writes ucT + xdbc partials
        gemm_cat<<<dim3(4, 64), 256, 0, stream>>>(xzuT, xpwl, cw, cb, ucT, xdbc, xp123);
        // dltT (softplus, sums partials) + fused BT/CT transpose
        dtbc<<<512, 256, 0, stream>>>(xdbc, xp123, dtw, dtb, dltT, BT, CT);
        // scan -> ybb
        scan_chunked<<<512, 1024, 0, stream>>>(dltT, ucT, BT, CT, szT,
                                               Ac + (size_t)l * 8192, Dl, ybb);
        // h0 += ybb @ opw.T; layer0: +LN(layer1)->hnb; layer1: ->h0b bf16 only
        if (l == 0)
            rowgemm<<<256, 512, 0, stream>>>(ybb, nullptr, opwl, nullptr, h0,
                                             nullptr, nullptr, 0,
                                             blk_ng + 256, blk_nb + 256,
                                             h0, hnb, nullptr,
                                             nullptr, nullptr, nullptr, 512);
        else
            rowgemm<<<256, 512, 0, stream>>>(ybb, nullptr, opwl, nullptr, h0,
                                             nullptr, nullptr, 0,
                                             nullptr, nullptr,
                                             nullptr, h0b, nullptr,
                                             nullptr, nullptr, nullptr, 512);
    }

    // final: h2 = gelu(h0b @ op_w.T + op_b); fused L2 scalar + cls GEMM -> out
    rowgemm<<<256, 512, 0, stream>>>(h0b, nullptr, op_wb, op_b, nullptr,
                                     nullptr, nullptr, 1,
                                     nullptr, nullptr,
                                     nullptr, nullptr, out + (size_t)BL * 128,
                                     cls_wb, cls_b, out, 256);
}

// Round 15
// 329.586 us; speedup vs baseline: 1.1027x; 1.1027x over previous
//
#include <hip/hip_runtime.h>
#include <hip/hip_bf16.h>
#include <math.h>

typedef __attribute__((ext_vector_type(8))) short frag8;   // 8 bf16 (4 VGPRs)
typedef __attribute__((ext_vector_type(4))) float f32x4;

// ---------------- device helpers ----------------
__device__ __forceinline__ float gelu_exact(float x) {
    return 0.5f * x * (1.0f + erff(x * 0.70710678118654752f));
}
__device__ __forceinline__ float softplus_f(float x) {
    return (x > 20.0f) ? x : log1pf(expf(x));
}
__device__ __forceinline__ float sigmoid_f(float x) {
    return 1.0f / (1.0f + __expf(-x));
}
__device__ __forceinline__ unsigned short bf16bits(float x) {
    __hip_bfloat16 h = __float2bfloat16(x);
    return *(unsigned short*)&h;
}
__device__ __forceinline__ float bf2f(unsigned short u) {
    unsigned int v = ((unsigned int)u) << 16;
    return __builtin_bit_cast(float, v);
}
// sum over the 16 lanes of each DPP row-of-16 — VALU-pipe only
__device__ __forceinline__ float row_sum16(float x) {
    int t;
    t = __builtin_amdgcn_update_dpp(0, __builtin_bit_cast(int, x), 0x128, 0xf, 0xf, true); // row_ror:8
    x += __builtin_bit_cast(float, t);
    t = __builtin_amdgcn_update_dpp(0, __builtin_bit_cast(int, x), 0x124, 0xf, 0xf, true); // row_ror:4
    x += __builtin_bit_cast(float, t);
    t = __builtin_amdgcn_update_dpp(0, __builtin_bit_cast(int, x), 0x122, 0xf, 0xf, true); // row_ror:2
    x += __builtin_bit_cast(float, t);
    t = __builtin_amdgcn_update_dpp(0, __builtin_bit_cast(int, x), 0x121, 0xf, 0xf, true); // row_ror:1
    x += __builtin_bit_cast(float, t);
    return x;
}
// inclusive prefix sum over the full 64-lane wave (DPP, VALU-pipe only)
__device__ __forceinline__ float prefix_sum64(float x) {
    int t;
    t = __builtin_amdgcn_update_dpp(0, __builtin_bit_cast(int, x), 0x111, 0xf, 0xf, true); // row_shr:1
    x += __builtin_bit_cast(float, t);
    t = __builtin_amdgcn_update_dpp(0, __builtin_bit_cast(int, x), 0x112, 0xf, 0xf, true); // row_shr:2
    x += __builtin_bit_cast(float, t);
    t = __builtin_amdgcn_update_dpp(0, __builtin_bit_cast(int, x), 0x114, 0xf, 0xf, true); // row_shr:4
    x += __builtin_bit_cast(float, t);
    t = __builtin_amdgcn_update_dpp(0, __builtin_bit_cast(int, x), 0x118, 0xf, 0xf, true); // row_shr:8
    x += __builtin_bit_cast(float, t);
    t = __builtin_amdgcn_update_dpp(0, __builtin_bit_cast(int, x), 0x142, 0xa, 0xf, true); // row_bcast:15
    x += __builtin_bit_cast(float, t);
    t = __builtin_amdgcn_update_dpp(0, __builtin_bit_cast(int, x), 0x143, 0xc, 0xf, true); // row_bcast:31
    x += __builtin_bit_cast(float, t);
    return x;
}

// ---------------- fp32 -> bf16 weight conversion + Acoef setup + l2 zero --------
struct CvtArgs {
    const float* src[6];
    unsigned short* dst[6];
    int n4[6];
};
__global__ __launch_bounds__(256)
void cvt_all(CvtArgs a, int total4, const float* __restrict__ Alog,
             float* __restrict__ Ac, float* l2)
{
    int i = blockIdx.x * 256 + threadIdx.x;
    if (i >= total4) {
        int j = i - total4;
        if (j < 16384) Ac[j] = -__expf(Alog[j]);
        if (j == 0) *l2 = 0.0f;
        return;
    }
    int seg = 0;
    while (i >= a.n4[seg]) { i -= a.n4[seg]; seg++; }
    float4 v = reinterpret_cast<const float4*>(a.src[seg])[i];
    ushort4 o;
    o.x = bf16bits(v.x); o.y = bf16bits(v.y); o.z = bf16bits(v.z); o.w = bf16bits(v.w);
    reinterpret_cast<ushort4*>(a.dst[seg])[i] = o;
}

// ---------------- ipw GEMM (N=1024, K=256): u-half -> xzuT fp32 [b][d][t],
// ---------------- z-half -> silu(z) bf16 szT [b][d][t] ----------------
__global__ __launch_bounds__(256)
void gemm_ipw(const unsigned short* __restrict__ A,
              const unsigned short* __restrict__ W,
              float* __restrict__ xzuT,
              unsigned short* __restrict__ szT)
{
    __shared__ __align__(16) unsigned short As[64][40];
    __shared__ __align__(16) unsigned short Bs[64][40];

    const int tid = threadIdx.x;
    const int wid = tid >> 6, lane = tid & 63;
    const int wm = (wid >> 1) * 32, wn = (wid & 1) * 32;
    const int m0 = blockIdx.y * 64, n0 = blockIdx.x * 64;
    const int lrow = lane & 15, quad = lane >> 4;
    const int K = 256;

    const int sm = tid >> 2;
    const int sk = (tid & 3) * 8;

    f32x4 acc[2][2] = {};

    for (int k0 = 0; k0 < K; k0 += 32) {
        float4 av = *reinterpret_cast<const float4*>(A + (size_t)(m0 + sm) * K + k0 + sk);
        *reinterpret_cast<float4*>(&As[sm][sk]) = av;
        float4 bv = *reinterpret_cast<const float4*>(W + (size_t)(n0 + sm) * K + k0 + sk);
        *reinterpret_cast<float4*>(&Bs[sm][sk]) = bv;
        __syncthreads();

        frag8 a0 = *reinterpret_cast<const frag8*>(&As[wm + lrow][quad * 8]);
        frag8 a1 = *reinterpret_cast<const frag8*>(&As[wm + 16 + lrow][quad * 8]);
        frag8 b0 = *reinterpret_cast<const frag8*>(&Bs[wn + lrow][quad * 8]);
        frag8 b1 = *reinterpret_cast<const frag8*>(&Bs[wn + 16 + lrow][quad * 8]);

        acc[0][0] = __builtin_amdgcn_mfma_f32_16x16x32_bf16(a0, b0, acc[0][0], 0, 0, 0);
        acc[0][1] = __builtin_amdgcn_mfma_f32_16x16x32_bf16(a0, b1, acc[0][1], 0, 0, 0);
        acc[1][0] = __builtin_amdgcn_mfma_f32_16x16x32_bf16(a1, b0, acc[1][0], 0, 0, 0);
        acc[1][1] = __builtin_amdgcn_mfma_f32_16x16x32_bf16(a1, b1, acc[1][1], 0, 0, 0);
        __syncthreads();
    }

    const int bb = m0 >> 10;
    const int tb = m0 & 1023;
    #pragma unroll
    for (int mi = 0; mi < 2; mi++) {
        int t4 = tb + wm + mi * 16 + quad * 4;
        #pragma unroll
        for (int nj = 0; nj < 2; nj++) {
            int col = n0 + wn + nj * 16 + lrow;
            if (col < 512) {
                float4 o = { acc[mi][nj][0], acc[mi][nj][1], acc[mi][nj][2], acc[mi][nj][3] };
                *reinterpret_cast<float4*>(xzuT + ((size_t)(bb * 512 + col)) * 1024 + t4) = o;
            } else {
                int z = col - 512;
                ushort4 o;
                float v0 = acc[mi][nj][0], v1 = acc[mi][nj][1], v2 = acc[mi][nj][2], v3 = acc[mi][nj][3];
                o.x = bf16bits(v0 * sigmoid_f(v0));
                o.y = bf16bits(v1 * sigmoid_f(v1));
                o.z = bf16bits(v2 * sigmoid_f(v2));
                o.w = bf16bits(v3 * sigmoid_f(v3));
                *reinterpret_cast<ushort4*>(szT + ((size_t)(bb * 512 + z)) * 1024 + t4) = o;
            }
        }
    }
}

// ---------------- conv4+SiLU fused into xpw projection, K-split x4 --------------
__global__ __launch_bounds__(256)
void gemm_cat(const float* __restrict__ xzuT,
              const unsigned short* __restrict__ W,     // xpw: 48 x 512 bf16
              const float* __restrict__ cw, const float* __restrict__ cb,
              float* __restrict__ ucT,
              float* __restrict__ xp0, float* __restrict__ xp123)
{
    __shared__ __align__(16) unsigned short As[64][40];
    __shared__ __align__(16) unsigned short Bs[64][40];

    const int tid = threadIdx.x;
    const int wid = tid >> 6, lane = tid & 63;
    const int wm = (wid >> 1) * 32, wn = (wid & 1) * 32;
    const int kc = blockIdx.x;            // 0..3 (128-d chunk)
    const int m0 = blockIdx.y * 64;
    const int bb = m0 >> 10;
    const int tb = m0 & 1023;
    const int lrow = lane & 15, quad = lane >> 4;
    const int N = 48;

    const int sm = tid >> 2;
    const int sk = (tid & 3) * 8;

    f32x4 acc[2][2] = {};

    for (int k0 = 0; k0 < 128; k0 += 32) {
        #pragma unroll
        for (int p = 0; p < 2; p++) {
            int kk = (tid >> 4) + p * 16;
            int k  = kc * 128 + k0 + kk;
            int mq = tid & 15;
            int tg = tb + mq * 4;
            const float* rowp = xzuT + ((size_t)(bb * 512 + k)) * 1024;
            float4 cur = *reinterpret_cast<const float4*>(rowp + tg);
            float4 prev = {0.f, 0.f, 0.f, 0.f};
            if (tg != 0) prev = *reinterpret_cast<const float4*>(rowp + tg - 4);
            float4 cv = *reinterpret_cast<const float4*>(cw + k * 4);
            float cbv = cb[k];
            float o0 = cbv + cv.x*prev.y + cv.y*prev.z + cv.z*prev.w + cv.w*cur.x;
            float o1 = cbv + cv.x*prev.z + cv.y*prev.w + cv.z*cur.x  + cv.w*cur.y;
            float o2 = cbv + cv.x*prev.w + cv.y*cur.x  + cv.z*cur.y  + cv.w*cur.z;
            float o3 = cbv + cv.x*cur.x  + cv.y*cur.y  + cv.z*cur.z  + cv.w*cur.w;
            o0 *= sigmoid_f(o0); o1 *= sigmoid_f(o1);
            o2 *= sigmoid_f(o2); o3 *= sigmoid_f(o3);
            float4 uo = { o0, o1, o2, o3 };
            *reinterpret_cast<float4*>(ucT + ((size_t)(bb * 512 + k)) * 1024 + tg) = uo;
            As[mq * 4 + 0][kk] = bf16bits(o0);
            As[mq * 4 + 1][kk] = bf16bits(o1);
            As[mq * 4 + 2][kk] = bf16bits(o2);
            As[mq * 4 + 3][kk] = bf16bits(o3);
        }
        float4 bv = {0.f, 0.f, 0.f, 0.f};
        if (sm < N) bv = *reinterpret_cast<const float4*>(W + (size_t)sm * 512 + kc * 128 + k0 + sk);
        *reinterpret_cast<float4*>(&Bs[sm][sk]) = bv;
        __syncthreads();

        frag8 a0 = *reinterpret_cast<const frag8*>(&As[wm + lrow][quad * 8]);
        frag8 a1 = *reinterpret_cast<const frag8*>(&As[wm + 16 + lrow][quad * 8]);
        frag8 b0 = *reinterpret_cast<const frag8*>(&Bs[wn + lrow][quad * 8]);
        frag8 b1 = *reinterpret_cast<const frag8*>(&Bs[wn + 16 + lrow][quad * 8]);

        acc[0][0] = __builtin_amdgcn_mfma_f32_16x16x32_bf16(a0, b0, acc[0][0], 0, 0, 0);
        acc[0][1] = __builtin_amdgcn_mfma_f32_16x16x32_bf16(a0, b1, acc[0][1], 0, 0, 0);
        acc[1][0] = __builtin_amdgcn_mfma_f32_16x16x32_bf16(a1, b0, acc[1][0], 0, 0, 0);
        acc[1][1] = __builtin_amdgcn_mfma_f32_16x16x32_bf16(a1, b1, acc[1][1], 0, 0, 0);
        __syncthreads();
    }

    float* C = (kc == 0) ? xp0 : (xp123 + (size_t)(kc - 1) * 4096 * 48);
    #pragma unroll
    for (int mi = 0; mi < 2; mi++) {
        #pragma unroll
        for (int nj = 0; nj < 2; nj++) {
            int col = wn + nj * 16 + lrow;
            if (col >= N) continue;
            #pragma unroll
            for (int r = 0; r < 4; r++) {
                int row = m0 + wm + mi * 16 + quad * 4 + r;
                C[(size_t)row * N + col] = acc[mi][nj][r];
            }
        }
    }
}

// ---------------- full-row GEMM (N=256), 512 threads / 8 waves ------------------
// Af != nullptr: stage A from fp32 (converting); else from bf16 A.
__global__ __launch_bounds__(512)
void rowgemm(const unsigned short* __restrict__ A,
             const float* __restrict__ Af,
             const unsigned short* __restrict__ W,
             const float* __restrict__ bias,
             const float* res,
             const float* g1, const float* b1, int gelu1,
             const float* g2, const float* b2,
             float* outF, unsigned short* outB, float* l2out,
             const unsigned short* clsW, const float* clsB, float* clsOut,
             int K)
{
    __shared__ __align__(16) unsigned short As[16][40];
    __shared__ __align__(16) unsigned short Bs[256][40];
    __shared__ float red[8][16][2];
    __shared__ float sq[16];
    __shared__ __align__(16) unsigned short hb[16][264];

    const int tid = threadIdx.x;
    const int w = tid >> 6, lane = tid & 63;
    const int lrow = lane & 15, quad = lane >> 4;
    const int m0 = blockIdx.x * 16;

    f32x4 acc[2] = {};

    for (int k0 = 0; k0 < K; k0 += 32) {
        if (tid < 64) {
            int r_ = tid >> 2, c8 = (tid & 3) * 8;
            if (Af) {
                float4 v0 = *reinterpret_cast<const float4*>(Af + (size_t)(m0 + r_) * K + k0 + c8);
                float4 v1 = *reinterpret_cast<const float4*>(Af + (size_t)(m0 + r_) * K + k0 + c8 + 4);
                unsigned short* dst = &As[r_][c8];
                dst[0] = bf16bits(v0.x); dst[1] = bf16bits(v0.y);
                dst[2] = bf16bits(v0.z); dst[3] = bf16bits(v0.w);
                dst[4] = bf16bits(v1.x); dst[5] = bf16bits(v1.y);
                dst[6] = bf16bits(v1.z); dst[7] = bf16bits(v1.w);
            } else {
                float4 av = *reinterpret_cast<const float4*>(A + (size_t)(m0 + r_) * K + k0 + c8);
                *reinterpret_cast<float4*>(&As[r_][c8]) = av;
            }
        }
        #pragma unroll
        for (int i = 0; i < 2; i++) {
            int n = (tid >> 2) + i * 128;
            float4 bv = *reinterpret_cast<const float4*>(W + (size_t)n * K + k0 + (tid & 3) * 8);
            *reinterpret_cast<float4*>(&Bs[n][(tid & 3) * 8]) = bv;
        }
        __syncthreads();
        frag8 a = *reinterpret_cast<const frag8*>(&As[lrow][quad * 8]);
        #pragma unroll
        for (int nj = 0; nj < 2; nj++) {
            frag8 b = *reinterpret_cast<const frag8*>(&Bs[w * 32 + nj * 16 + lrow][quad * 8]);
            acc[nj] = __builtin_amdgcn_mfma_f32_16x16x32_bf16(a, b, acc[nj], 0, 0, 0);
        }
        __syncthreads();
    }

    float v[2][4];
    #pragma unroll
    for (int nj = 0; nj < 2; nj++) {
        int col = w * 32 + nj * 16 + lrow;
        #pragma unroll
        for (int r = 0; r < 4; r++) {
            int row = m0 + quad * 4 + r;
            float t = acc[nj][r];
            if (bias) t += bias[col];
            if (res) t += res[(size_t)row * 256 + col];
            v[nj][r] = t;
        }
    }

    if (g1) {
        #pragma unroll
        for (int r = 0; r < 4; r++) {
            float s1 = v[0][r] + v[1][r];
            float s2 = v[0][r]*v[0][r] + v[1][r]*v[1][r];
            s1 = row_sum16(s1); s2 = row_sum16(s2);
            if (lrow == 0) { red[w][quad * 4 + r][0] = s1; red[w][quad * 4 + r][1] = s2; }
        }
        __syncthreads();
        #pragma unroll
        for (int r = 0; r < 4; r++) {
            int rr = quad * 4 + r;
            float t1 = 0.f, t2 = 0.f;
            #pragma unroll
            for (int ww = 0; ww < 8; ww++) { t1 += red[ww][rr][0]; t2 += red[ww][rr][1]; }
            float mu = t1 * (1.0f / 256.0f);
            float var = t2 * (1.0f / 256.0f) - mu * mu;
            float rstd = rsqrtf(var + 1e-5f);
            #pragma unroll
            for (int nj = 0; nj < 2; nj++) {
                int col = w * 32 + nj * 16 + lrow;
                float t = (v[nj][r] - mu) * rstd * g1[col] + b1[col];
                if (gelu1) t = gelu_exact(t);
                v[nj][r] = t;
            }
        }
        __syncthreads();
    } else if (gelu1) {
        #pragma unroll
        for (int nj = 0; nj < 2; nj++)
            #pragma unroll
            for (int r = 0; r < 4; r++)
                v[nj][r] = gelu_exact(v[nj][r]);
    }

    if (outF) {
        #pragma unroll
        for (int nj = 0; nj < 2; nj++) {
            int col = w * 32 + nj * 16 + lrow;
            #pragma unroll
            for (int r = 0; r < 4; r++)
                outF[(size_t)(m0 + quad * 4 + r) * 256 + col] = v[nj][r];
        }
    }

    if (l2out) {
        #pragma unroll
        for (int r = 0; r < 4; r++) {
            float s2 = v[0][r]*v[0][r] + v[1][r]*v[1][r];
            s2 = row_sum16(s2);
            if (lrow == 0) red[w][quad * 4 + r][0] = s2;
        }
        __syncthreads();
        if (tid < 16) {
            float t = 0.f;
            #pragma unroll
            for (int ww = 0; ww < 8; ww++) t += red[ww][tid][0];
            sq[tid] = sqrtf(t);
        }
        __syncthreads();
        if (tid == 0) {
            float a = 0.f;
            #pragma unroll
            for (int i = 0; i < 16; i++) a += sq[i];
            atomicAdd(l2out, a * (0.01f / 4096.0f));
        }
    }

    if (g2) {
        __syncthreads();
        #pragma unroll
        for (int r = 0; r < 4; r++) {
            float s1 = v[0][r] + v[1][r];
            float s2 = v[0][r]*v[0][r] + v[1][r]*v[1][r];
            s1 = row_sum16(s1); s2 = row_sum16(s2);
            if (lrow == 0) { red[w][quad * 4 + r][0] = s1; red[w][quad * 4 + r][1] = s2; }
        }
        __syncthreads();
        #pragma unroll
        for (int r = 0; r < 4; r++) {
            int rr = quad * 4 + r;
            float t1 = 0.f, t2 = 0.f;
            #pragma unroll
            for (int ww = 0; ww < 8; ww++) { t1 += red[ww][rr][0]; t2 += red[ww][rr][1]; }
            float mu = t1 * (1.0f / 256.0f);
            float var = t2 * (1.0f / 256.0f) - mu * mu;
            float rstd = rsqrtf(var + 1e-5f);
            #pragma unroll
            for (int nj = 0; nj < 2; nj++) {
                int col = w * 32 + nj * 16 + lrow;
                outB[(size_t)(m0 + rr) * 256 + col] = bf16bits((v[nj][r] - mu) * rstd * g2[col] + b2[col]);
            }
        }
    } else if (outB) {
        #pragma unroll
        for (int nj = 0; nj < 2; nj++) {
            int col = w * 32 + nj * 16 + lrow;
            #pragma unroll
            for (int r = 0; r < 4; r++)
                outB[(size_t)(m0 + quad * 4 + r) * 256 + col] = bf16bits(v[nj][r]);
        }
    }

    // ---- fused cls GEMM: logits(16 x 128) = v(16 x 256) @ clsW(128 x 256)^T ----
    if (clsW) {
        #pragma unroll
        for (int nj = 0; nj < 2; nj++) {
            int col = w * 32 + nj * 16 + lrow;
            #pragma unroll
            for (int r = 0; r < 4; r++)
                hb[quad * 4 + r][col] = bf16bits(v[nj][r]);
        }
        __syncthreads();
        f32x4 cacc = {};
        #pragma unroll
        for (int k0 = 0; k0 < 256; k0 += 32) {
            frag8 a = *reinterpret_cast<const frag8*>(&hb[lrow][k0 + quad * 8]);
            frag8 b = *reinterpret_cast<const frag8*>(clsW + (size_t)(w * 16 + lrow) * 256 + k0 + quad * 8);
            cacc = __builtin_amdgcn_mfma_f32_16x16x32_bf16(a, b, cacc, 0, 0, 0);
        }
        int col = w * 16 + lrow;
        float cb = clsB[col];
        #pragma unroll
        for (int r = 0; r < 4; r++)
            clsOut[(size_t)(m0 + quad * 4 + r) * 128 + col] = cacc[r] + cb;
    }
}

// ---------------- dt proj + softplus -> dltT ; fused B/C transpose --------------
__global__ __launch_bounds__(256)
void dtbc(const float* __restrict__ xp0, const float* __restrict__ xp123,
          const float* __restrict__ dtw,
          const float* __restrict__ dtb, float* __restrict__ dltT,
          float* __restrict__ BT, float* __restrict__ CT)
{
    __shared__ float xd[64][17];
    __shared__ float wS[64][16];
    __shared__ float bS[64];
    const size_t S = (size_t)4096 * 48;
    const int bx = blockIdx.x;
    const int b = bx >> 7;
    const int tt = (bx >> 3) & 15;
    const int dg = bx & 7;
    const int tid = threadIdx.x;
    const int t0 = tt * 64, d0 = dg * 64;

    for (int i = tid; i < 64 * 16; i += 256) {
        int t = i >> 4, k = i & 15;
        size_t off = ((size_t)(b * 1024 + t0 + t)) * 48 + k;
        xd[t][k] = xp0[off] + xp123[off] + xp123[S + off] + xp123[2 * S + off];
    }
    for (int i = tid; i < 64 * 16; i += 256) {
        int dl = i >> 4, k = i & 15;
        wS[dl][k] = dtw[(d0 + dl) * 16 + k];
    }
    if (tid < 64) bS[tid] = dtb[d0 + tid];
    __syncthreads();

    const int tl = tid & 63, w = tid >> 6;
    #pragma unroll 4
    for (int di = 0; di < 16; di++) {
        int dl = w * 16 + di;
        float acc = bS[dl];
        #pragma unroll
        for (int k = 0; k < 16; k++) acc += xd[tl][k] * wS[dl][k];
        dltT[((size_t)(b * 512 + d0 + dl)) * 1024 + t0 + tl] = softplus_f(acc);
    }

    {
        int c = tid >> 6;
        int t = tid & 63;
        int col = dg * 4 + c;
        size_t off = ((size_t)(b * 1024 + t0 + t)) * 48 + 16 + col;
        float v = xp0[off] + xp123[off] + xp123[S + off] + xp123[2 * S + off];
        if (col < 16) BT[((size_t)(b * 16 + col)) * 1024 + t0 + t] = v;
        else          CT[((size_t)(b * 16 + col - 16)) * 1024 + t0 + t] = v;
    }
}

// ---------------- chunked selective scan (1 barrier, decentralized combine) -----
__global__ __launch_bounds__(1024)
void scan_chunked(const float* __restrict__ dltT, const float* __restrict__ ucT,
                  const float* __restrict__ BT, const float* __restrict__ CT,
                  const unsigned short* __restrict__ szT,
                  const float* __restrict__ Ac,
                  const float* __restrict__ Dp,
                  unsigned short* __restrict__ y)
{
    __shared__ float aprod_s[16][64];
    __shared__ float sfin_s[16][64];
    __shared__ float sin_w[16][64];
    __shared__ __align__(16) float ylocal[16][64][4];

    const int j = blockIdx.x;
    const int bid = (j & 7) * 64 + (j >> 3);     // XCD swizzle
    const int b = bid >> 7;
    const int d0 = (bid & 127) * 4;
    const int w = threadIdx.x >> 6;
    const int lane = threadIdx.x & 63;
    const int dsub = lane >> 4, s = lane & 15;
    const int d = d0 + dsub;

    const float Acoef = Ac[d * 16 + s];

    const float4* dp = reinterpret_cast<const float4*>(dltT + ((size_t)(b * 512 + d)) * 1024 + w * 64);
    const float4* up = reinterpret_cast<const float4*>(ucT  + ((size_t)(b * 512 + d)) * 1024 + w * 64);
    const float4* Bp = reinterpret_cast<const float4*>(BT + ((size_t)(b * 16 + s)) * 1024 + w * 64);
    const float4* Cp = reinterpret_cast<const float4*>(CT + ((size_t)(b * 16 + s)) * 1024 + w * 64);

    // ---- Phase A: local scan with cumprod (q+1 prefetch) ----
    float st = 0.0f, ap = 1.0f;
    float4 dt4 = dp[0], ut4 = up[0], B4 = Bp[0], C4 = Cp[0];
    #pragma unroll
    for (int q = 0; q < 16; q++) {
        float4 ndt, nut, nB, nC;
        if (q < 15) { ndt = dp[q + 1]; nut = up[q + 1]; nB = Bp[q + 1]; nC = Cp[q + 1]; }
        const float* dtp = (const float*)&dt4;
        const float* utp = (const float*)&ut4;
        const float* Btp = (const float*)&B4;
        const float* Ctp = (const float*)&C4;
        #pragma unroll
        for (int jj = 0; jj < 4; jj++) {
            float dA = __expf(dtp[jj] * Acoef);
            st = st * dA + dtp[jj] * utp[jj] * Btp[jj];
            ap *= dA;
            float part = row_sum16(st * Ctp[jj]);
            if (s == 0) ylocal[w][q * 4 + jj][dsub] = part;
        }
        dt4 = ndt; ut4 = nut; B4 = nB; C4 = nC;
    }
    aprod_s[w][lane] = ap;
    sfin_s[w][lane] = st;
    __syncthreads();                                 // the only barrier

    // ---- decentralized combine ----
    {
        float pre = 0.0f;
        #pragma unroll
        for (int c = 0; c < 15; c++) {
            float apc = aprod_s[c][lane];
            float sfc = sfin_s[c][lane];
            float cand = sfc + apc * pre;
            pre = (c < w) ? cand : pre;
        }
        sin_w[w][lane] = pre;
    }

    // ---- Phase C: lane = t; correction via prefix sums + epilogue ----
    const int t = w * 64 + lane;
    float cums[4];
    #pragma unroll
    for (int dd = 0; dd < 4; dd++)
        cums[dd] = dltT[((size_t)(b * 512 + d0 + dd)) * 1024 + t];
    #pragma unroll
    for (int dd = 0; dd < 4; dd++)
        cums[dd] = prefix_sum64(cums[dd]);

    float4 yl = *reinterpret_cast<const float4*>(&ylocal[w][lane][0]);
    float acc[4] = { yl.x, yl.y, yl.z, yl.w };

    #pragma unroll
    for (int sq = 0; sq < 4; sq++) {
        float Cs[4];
        #pragma unroll
        for (int jj = 0; jj < 4; jj++)
            Cs[jj] = CT[((size_t)(b * 16 + sq * 4 + jj)) * 1024 + t];
        #pragma unroll
        for (int dd = 0; dd < 4; dd++) {
            float4 sin4 = *reinterpret_cast<const float4*>(&sin_w[w][dd * 16 + sq * 4]);
            const float* sp = (const float*)&sin4;
            #pragma unroll
            for (int jj = 0; jj < 4; jj++) {
                float ac = Ac[(d0 + dd) * 16 + sq * 4 + jj];
                acc[dd] += sp[jj] * Cs[jj] * __expf(ac * cums[dd]);
            }
        }
    }

    const size_t row = (size_t)b * 1024 + t;
    #pragma unroll
    for (int dd = 0; dd < 4; dd++) {
        float ut = ucT[((size_t)(b * 512 + d0 + dd)) * 1024 + t];
        float sz = bf2f(szT[((size_t)(b * 512 + d0 + dd)) * 1024 + t]);
        float yv = acc[dd] + ut * Dp[d0 + dd];
        y[row * 512 + d0 + dd] = bf16bits(yv * sz);
    }
}

// ---------------- launcher ----------------
extern "C" void kernel_launch(void* const* d_in, const int* in_sizes, int n_in,
                              void* d_out, int out_size, void* d_ws, size_t ws_size,
                              hipStream_t stream)
{
    const float* x      = (const float*)d_in[0];
    const float* in_b   = (const float*)d_in[2];
    const float* ln_g   = (const float*)d_in[3];
    const float* ln_b   = (const float*)d_in[4];
    const float* blk_ng  = (const float*)d_in[5];
    const float* blk_nb  = (const float*)d_in[6];
    const float* blk_cw  = (const float*)d_in[8];
    const float* blk_cb  = (const float*)d_in[9];
    const float* blk_dtw = (const float*)d_in[11];
    const float* blk_dtb = (const float*)d_in[12];
    const float* blk_Alog= (const float*)d_in[13];
    const float* blk_D   = (const float*)d_in[14];
    const float* op_b   = (const float*)d_in[17];
    const float* cls_b  = (const float*)d_in[19];
    float* out = (float*)d_out;

    const int BL = 4096;
    float* ws = (float*)d_ws;
    float* h0   = ws;                         // 1,048,576
    float* xzuT = h0 + 1048576;               // 2,097,152  [b][d][t] fp32 (u pre-conv)
    float* ucT  = xzuT + 2097152;             // 2,097,152  [b][d][t]
    float* xdbc = ucT + 2097152;              //   196,608  (xdbcp chunk 0)
    float* dltT = xdbc + 196608;              // 2,097,152  [b][d][t]
    float* BT   = dltT + 2097152;             //    65,536  [b][s][t]
    float* CT   = BT + 65536;                 //    65,536  [b][s][t]
    float* Ac   = CT + 65536;                 //    16,384
    unsigned short* szT = (unsigned short*)(Ac + 16384);  // 2,097,152 bf16 [b][d][t]
    unsigned short* wb  = szT + 2097152;      // 1,130,496
    unsigned short* hnb = wb + 1130496;       // 1,048,576
    unsigned short* ybb = hnb + 1048576;      // 2,097,152
    unsigned short* h0b = hnb;
    float* xp123 = (float*)ybb;               // xdbcp chunks 1..3 (dead-ybb alias)
    unsigned short* in_wb  = wb;
    unsigned short* ipw_b  = wb + 196608;
    unsigned short* xpw_b  = wb + 720896;
    unsigned short* opw_b  = wb + 770048;
    unsigned short* op_wb  = wb + 1032192;
    unsigned short* cls_wb = wb + 1097728;

    CvtArgs ca;
    ca.src[0] = (const float*)d_in[1];  ca.dst[0] = in_wb;  ca.n4[0] = 196608 / 4;
    ca.src[1] = (const float*)d_in[7];  ca.dst[1] = ipw_b;  ca.n4[1] = 524288 / 4;
    ca.src[2] = (const float*)d_in[10]; ca.dst[2] = xpw_b;  ca.n4[2] = 49152 / 4;
    ca.src[3] = (const float*)d_in[15]; ca.dst[3] = opw_b;  ca.n4[3] = 262144 / 4;
    ca.src[4] = (const float*)d_in[16]; ca.dst[4] = op_wb;  ca.n4[4] = 65536 / 4;
    ca.src[5] = (const float*)d_in[18]; ca.dst[5] = cls_wb; ca.n4[5] = 32768 / 4;
    int total4 = 1130496 / 4;
    int totalg = total4 + 16384;
    cvt_all<<<(totalg + 255) / 256, 256, 0, stream>>>(ca, total4, blk_Alog, Ac,
                                                      out + (size_t)BL * 128);

    // in_proj (A from fp32 x) + bias + LN + GELU -> h0 (fp32), + LN(layer0) -> hnb
    rowgemm<<<256, 512, 0, stream>>>(nullptr, x, in_wb, in_b, nullptr,
                                     ln_g, ln_b, 1,
                                     blk_ng, blk_nb,
                                     h0, hnb, nullptr,
                                     nullptr, nullptr, nullptr, 768);

    for (int l = 0; l < 2; l++) {
        const float* cw   = blk_cw  + (size_t)l * 512 * 4;
        const float* cb   = blk_cb  + l * 512;
        const float* dtw  = blk_dtw + (size_t)l * 512 * 16;
        const float* dtb  = blk_dtb + l * 512;
        const float* Dl   = blk_D   + l * 512;
        const unsigned short* ipwl = ipw_b + (size_t)l * 262144;
        const unsigned short* xpwl = xpw_b + (size_t)l * 24576;
        const unsigned short* opwl = opw_b + (size_t)l * 131072;

        // ipw GEMM: u -> xzuT fp32 [b][d][t]; z -> silu(z) bf16 szT [b][d][t]
        gemm_ipw<<<dim3(16, 64), 256, 0, stream>>>(hnb, ipwl, xzuT, szT);
        // fused conv + xpw projection (K-split x4): writes ucT + xdbc partials
        gemm_cat<<<dim3(4, 64), 256, 0, stream>>>(xzuT, xpwl, cw, cb, ucT, xdbc, xp123);
        // dltT (softplus, sums partials) + fused BT/CT transpose
        dtbc<<<512, 256, 0, stream>>>(xdbc, xp123, dtw, dtb, dltT, BT, CT);
        // scan -> ybb
        scan_chunked<<<512, 1024, 0, stream>>>(dltT, ucT, BT, CT, szT,
                                               Ac + (size_t)l * 8192, Dl, ybb);
        // h0 += ybb @ opw.T; layer0: +LN(layer1)->hnb; layer1: ->h0b bf16 only
        if (l == 0)
            rowgemm<<<256, 512, 0, stream>>>(ybb, nullptr, opwl, nullptr, h0,
                                             nullptr, nullptr, 0,
                                             blk_ng + 256, blk_nb + 256,
                                             h0, hnb, nullptr,
                                             nullptr, nullptr, nullptr, 512);
        else
            rowgemm<<<256, 512, 0, stream>>>(ybb, nullptr, opwl, nullptr, h0,
                                             nullptr, nullptr, 0,
                                             nullptr, nullptr,
                                             nullptr, h0b, nullptr,
                                             nullptr, nullptr, nullptr, 512);
    }

    // final: h2 = gelu(h0b @ op_w.T + op_b); fused L2 scalar + cls GEMM -> out
    rowgemm<<<256, 512, 0, stream>>>(h0b, nullptr, op_wb, op_b, nullptr,
                                     nullptr, nullptr, 1,
                                     nullptr, nullptr,
                                     nullptr, nullptr, out + (size_t)BL * 128,
                                     cls_wb, cls_b, out, 256);
}

// Round 16
// 306.362 us; speedup vs baseline: 1.1863x; 1.0758x over previous
//
#include <hip/hip_runtime.h>
#include <hip/hip_bf16.h>
#include <math.h>

typedef __attribute__((ext_vector_type(8))) short frag8;   // 8 bf16 (4 VGPRs)
typedef __attribute__((ext_vector_type(4))) float f32x4;

// ---------------- device helpers ----------------
__device__ __forceinline__ float gelu_exact(float x) {
    return 0.5f * x * (1.0f + erff(x * 0.70710678118654752f));
}
__device__ __forceinline__ float softplus_f(float x) {
    return (x > 20.0f) ? x : log1pf(expf(x));
}
__device__ __forceinline__ float sigmoid_f(float x) {
    return 1.0f / (1.0f + __expf(-x));
}
__device__ __forceinline__ unsigned short bf16bits(float x) {
    __hip_bfloat16 h = __float2bfloat16(x);
    return *(unsigned short*)&h;
}
__device__ __forceinline__ float bf2f(unsigned short u) {
    unsigned int v = ((unsigned int)u) << 16;
    return __builtin_bit_cast(float, v);
}
// sum over the 16 lanes of each DPP row-of-16 — VALU-pipe only
__device__ __forceinline__ float row_sum16(float x) {
    int t;
    t = __builtin_amdgcn_update_dpp(0, __builtin_bit_cast(int, x), 0x128, 0xf, 0xf, true); // row_ror:8
    x += __builtin_bit_cast(float, t);
    t = __builtin_amdgcn_update_dpp(0, __builtin_bit_cast(int, x), 0x124, 0xf, 0xf, true); // row_ror:4
    x += __builtin_bit_cast(float, t);
    t = __builtin_amdgcn_update_dpp(0, __builtin_bit_cast(int, x), 0x122, 0xf, 0xf, true); // row_ror:2
    x += __builtin_bit_cast(float, t);
    t = __builtin_amdgcn_update_dpp(0, __builtin_bit_cast(int, x), 0x121, 0xf, 0xf, true); // row_ror:1
    x += __builtin_bit_cast(float, t);
    return x;
}
// inclusive prefix sum over the full 64-lane wave (DPP, VALU-pipe only)
__device__ __forceinline__ float prefix_sum64(float x) {
    int t;
    t = __builtin_amdgcn_update_dpp(0, __builtin_bit_cast(int, x), 0x111, 0xf, 0xf, true); // row_shr:1
    x += __builtin_bit_cast(float, t);
    t = __builtin_amdgcn_update_dpp(0, __builtin_bit_cast(int, x), 0x112, 0xf, 0xf, true); // row_shr:2
    x += __builtin_bit_cast(float, t);
    t = __builtin_amdgcn_update_dpp(0, __builtin_bit_cast(int, x), 0x114, 0xf, 0xf, true); // row_shr:4
    x += __builtin_bit_cast(float, t);
    t = __builtin_amdgcn_update_dpp(0, __builtin_bit_cast(int, x), 0x118, 0xf, 0xf, true); // row_shr:8
    x += __builtin_bit_cast(float, t);
    t = __builtin_amdgcn_update_dpp(0, __builtin_bit_cast(int, x), 0x142, 0xa, 0xf, true); // row_bcast:15
    x += __builtin_bit_cast(float, t);
    t = __builtin_amdgcn_update_dpp(0, __builtin_bit_cast(int, x), 0x143, 0xc, 0xf, true); // row_bcast:31
    x += __builtin_bit_cast(float, t);
    return x;
}

// -------- fp32->bf16 weight cvt + Acoef + l2 zero + zero xdt/BT/CT (both layers)
struct CvtArgs {
    const float* src[6];
    unsigned short* dst[6];
    int n4[6];
};
__global__ __launch_bounds__(256)
void cvt_all(CvtArgs a, int total4, const float* __restrict__ Alog,
             float* __restrict__ Ac, float* __restrict__ Z, int zquads, float* l2)
{
    int i = blockIdx.x * 256 + threadIdx.x;
    if (i >= total4) {
        int j = i - total4;
        if (j < 16384) {
            Ac[j] = -__expf(Alog[j]);
        } else {
            int z = j - 16384;
            if (z < zquads) {
                float4 zero = {0.f, 0.f, 0.f, 0.f};
                reinterpret_cast<float4*>(Z)[z] = zero;
            }
        }
        if (j == 0) *l2 = 0.0f;
        return;
    }
    int seg = 0;
    while (i >= a.n4[seg]) { i -= a.n4[seg]; seg++; }
    float4 v = reinterpret_cast<const float4*>(a.src[seg])[i];
    ushort4 o;
    o.x = bf16bits(v.x); o.y = bf16bits(v.y); o.z = bf16bits(v.z); o.w = bf16bits(v.w);
    reinterpret_cast<ushort4*>(a.dst[seg])[i] = o;
}

// ---------------- ipw GEMM (N=1024, K=256): u-half -> xzuT fp32 [b][d][t],
// ---------------- z-half -> silu(z) bf16 szT [b][d][t] ----------------
__global__ __launch_bounds__(256)
void gemm_ipw(const unsigned short* __restrict__ A,
              const unsigned short* __restrict__ W,
              float* __restrict__ xzuT,
              unsigned short* __restrict__ szT)
{
    __shared__ __align__(16) unsigned short As[64][40];
    __shared__ __align__(16) unsigned short Bs[64][40];

    const int tid = threadIdx.x;
    const int wid = tid >> 6, lane = tid & 63;
    const int wm = (wid >> 1) * 32, wn = (wid & 1) * 32;
    const int m0 = blockIdx.y * 64, n0 = blockIdx.x * 64;
    const int lrow = lane & 15, quad = lane >> 4;
    const int K = 256;

    const int sm = tid >> 2;
    const int sk = (tid & 3) * 8;

    f32x4 acc[2][2] = {};

    for (int k0 = 0; k0 < K; k0 += 32) {
        float4 av = *reinterpret_cast<const float4*>(A + (size_t)(m0 + sm) * K + k0 + sk);
        *reinterpret_cast<float4*>(&As[sm][sk]) = av;
        float4 bv = *reinterpret_cast<const float4*>(W + (size_t)(n0 + sm) * K + k0 + sk);
        *reinterpret_cast<float4*>(&Bs[sm][sk]) = bv;
        __syncthreads();

        frag8 a0 = *reinterpret_cast<const frag8*>(&As[wm + lrow][quad * 8]);
        frag8 a1 = *reinterpret_cast<const frag8*>(&As[wm + 16 + lrow][quad * 8]);
        frag8 b0 = *reinterpret_cast<const frag8*>(&Bs[wn + lrow][quad * 8]);
        frag8 b1 = *reinterpret_cast<const frag8*>(&Bs[wn + 16 + lrow][quad * 8]);

        acc[0][0] = __builtin_amdgcn_mfma_f32_16x16x32_bf16(a0, b0, acc[0][0], 0, 0, 0);
        acc[0][1] = __builtin_amdgcn_mfma_f32_16x16x32_bf16(a0, b1, acc[0][1], 0, 0, 0);
        acc[1][0] = __builtin_amdgcn_mfma_f32_16x16x32_bf16(a1, b0, acc[1][0], 0, 0, 0);
        acc[1][1] = __builtin_amdgcn_mfma_f32_16x16x32_bf16(a1, b1, acc[1][1], 0, 0, 0);
        __syncthreads();
    }

    const int bb = m0 >> 10;
    const int tb = m0 & 1023;
    #pragma unroll
    for (int mi = 0; mi < 2; mi++) {
        int t4 = tb + wm + mi * 16 + quad * 4;
        #pragma unroll
        for (int nj = 0; nj < 2; nj++) {
            int col = n0 + wn + nj * 16 + lrow;
            if (col < 512) {
                float4 o = { acc[mi][nj][0], acc[mi][nj][1], acc[mi][nj][2], acc[mi][nj][3] };
                *reinterpret_cast<float4*>(xzuT + ((size_t)(bb * 512 + col)) * 1024 + t4) = o;
            } else {
                int z = col - 512;
                ushort4 o;
                float v0 = acc[mi][nj][0], v1 = acc[mi][nj][1], v2 = acc[mi][nj][2], v3 = acc[mi][nj][3];
                o.x = bf16bits(v0 * sigmoid_f(v0));
                o.y = bf16bits(v1 * sigmoid_f(v1));
                o.z = bf16bits(v2 * sigmoid_f(v2));
                o.w = bf16bits(v3 * sigmoid_f(v3));
                *reinterpret_cast<ushort4*>(szT + ((size_t)(bb * 512 + z)) * 1024 + t4) = o;
            }
        }
    }
}

// ---------------- conv4+SiLU fused into xpw projection, K-split x4 --------------
// outputs via atomicAdd into zero-initialized xdt (row-major dt), BT, CT (transposed)
__global__ __launch_bounds__(256)
void gemm_cat(const float* __restrict__ xzuT,
              const unsigned short* __restrict__ W,     // xpw: 48 x 512 bf16
              const float* __restrict__ cw, const float* __restrict__ cb,
              float* __restrict__ ucT,
              float* __restrict__ xdt, float* __restrict__ BT, float* __restrict__ CT)
{
    __shared__ __align__(16) unsigned short As[64][40];
    __shared__ __align__(16) unsigned short Bs[64][40];

    const int tid = threadIdx.x;
    const int wid = tid >> 6, lane = tid & 63;
    const int wm = (wid >> 1) * 32, wn = (wid & 1) * 32;
    const int kc = blockIdx.x;            // 0..3 (128-d chunk)
    const int m0 = blockIdx.y * 64;
    const int bb = m0 >> 10;
    const int tb = m0 & 1023;
    const int lrow = lane & 15, quad = lane >> 4;
    const int N = 48;

    const int sm = tid >> 2;
    const int sk = (tid & 3) * 8;

    f32x4 acc[2][2] = {};

    for (int k0 = 0; k0 < 128; k0 += 32) {
        #pragma unroll
        for (int p = 0; p < 2; p++) {
            int kk = (tid >> 4) + p * 16;
            int k  = kc * 128 + k0 + kk;
            int mq = tid & 15;
            int tg = tb + mq * 4;
            const float* rowp = xzuT + ((size_t)(bb * 512 + k)) * 1024;
            float4 cur = *reinterpret_cast<const float4*>(rowp + tg);
            float4 prev = {0.f, 0.f, 0.f, 0.f};
            if (tg != 0) prev = *reinterpret_cast<const float4*>(rowp + tg - 4);
            float4 cv = *reinterpret_cast<const float4*>(cw + k * 4);
            float cbv = cb[k];
            float o0 = cbv + cv.x*prev.y + cv.y*prev.z + cv.z*prev.w + cv.w*cur.x;
            float o1 = cbv + cv.x*prev.z + cv.y*prev.w + cv.z*cur.x  + cv.w*cur.y;
            float o2 = cbv + cv.x*prev.w + cv.y*cur.x  + cv.z*cur.y  + cv.w*cur.z;
            float o3 = cbv + cv.x*cur.x  + cv.y*cur.y  + cv.z*cur.z  + cv.w*cur.w;
            o0 *= sigmoid_f(o0); o1 *= sigmoid_f(o1);
            o2 *= sigmoid_f(o2); o3 *= sigmoid_f(o3);
            float4 uo = { o0, o1, o2, o3 };
            *reinterpret_cast<float4*>(ucT + ((size_t)(bb * 512 + k)) * 1024 + tg) = uo;
            As[mq * 4 + 0][kk] = bf16bits(o0);
            As[mq * 4 + 1][kk] = bf16bits(o1);
            As[mq * 4 + 2][kk] = bf16bits(o2);
            As[mq * 4 + 3][kk] = bf16bits(o3);
        }
        float4 bv = {0.f, 0.f, 0.f, 0.f};
        if (sm < N) bv = *reinterpret_cast<const float4*>(W + (size_t)sm * 512 + kc * 128 + k0 + sk);
        *reinterpret_cast<float4*>(&Bs[sm][sk]) = bv;
        __syncthreads();

        frag8 a0 = *reinterpret_cast<const frag8*>(&As[wm + lrow][quad * 8]);
        frag8 a1 = *reinterpret_cast<const frag8*>(&As[wm + 16 + lrow][quad * 8]);
        frag8 b0 = *reinterpret_cast<const frag8*>(&Bs[wn + lrow][quad * 8]);
        frag8 b1 = *reinterpret_cast<const frag8*>(&Bs[wn + 16 + lrow][quad * 8]);

        acc[0][0] = __builtin_amdgcn_mfma_f32_16x16x32_bf16(a0, b0, acc[0][0], 0, 0, 0);
        acc[0][1] = __builtin_amdgcn_mfma_f32_16x16x32_bf16(a0, b1, acc[0][1], 0, 0, 0);
        acc[1][0] = __builtin_amdgcn_mfma_f32_16x16x32_bf16(a1, b0, acc[1][0], 0, 0, 0);
        acc[1][1] = __builtin_amdgcn_mfma_f32_16x16x32_bf16(a1, b1, acc[1][1], 0, 0, 0);
        __syncthreads();
    }

    #pragma unroll
    for (int mi = 0; mi < 2; mi++) {
        #pragma unroll
        for (int nj = 0; nj < 2; nj++) {
            int col = wn + nj * 16 + lrow;
            if (col >= N) continue;
            #pragma unroll
            for (int r = 0; r < 4; r++) {
                int trow = tb + wm + mi * 16 + quad * 4 + r;     // t within batch
                float v = acc[mi][nj][r];
                if (col < 16)
                    atomicAdd(&xdt[((size_t)(bb * 1024 + trow)) * 16 + col], v);
                else if (col < 32)
                    atomicAdd(&BT[((size_t)(bb * 16 + col - 16)) * 1024 + trow], v);
                else
                    atomicAdd(&CT[((size_t)(bb * 16 + col - 32)) * 1024 + trow], v);
            }
        }
    }
}

// ---------------- full-row GEMM (N=256), 512 threads / 8 waves ------------------
__global__ __launch_bounds__(512)
void rowgemm(const unsigned short* __restrict__ A,
             const float* __restrict__ Af,
             const unsigned short* __restrict__ W,
             const float* __restrict__ bias,
             const float* res,
             const float* g1, const float* b1, int gelu1,
             const float* g2, const float* b2,
             float* outF, unsigned short* outB, float* l2out,
             const unsigned short* clsW, const float* clsB, float* clsOut,
             int K)
{
    __shared__ __align__(16) unsigned short As[16][40];
    __shared__ __align__(16) unsigned short Bs[256][40];
    __shared__ float red[8][16][2];
    __shared__ float sq[16];
    __shared__ __align__(16) unsigned short hb[16][264];

    const int tid = threadIdx.x;
    const int w = tid >> 6, lane = tid & 63;
    const int lrow = lane & 15, quad = lane >> 4;
    const int m0 = blockIdx.x * 16;

    f32x4 acc[2] = {};

    for (int k0 = 0; k0 < K; k0 += 32) {
        if (tid < 64) {
            int r_ = tid >> 2, c8 = (tid & 3) * 8;
            if (Af) {
                float4 v0 = *reinterpret_cast<const float4*>(Af + (size_t)(m0 + r_) * K + k0 + c8);
                float4 v1 = *reinterpret_cast<const float4*>(Af + (size_t)(m0 + r_) * K + k0 + c8 + 4);
                unsigned short* dst = &As[r_][c8];
                dst[0] = bf16bits(v0.x); dst[1] = bf16bits(v0.y);
                dst[2] = bf16bits(v0.z); dst[3] = bf16bits(v0.w);
                dst[4] = bf16bits(v1.x); dst[5] = bf16bits(v1.y);
                dst[6] = bf16bits(v1.z); dst[7] = bf16bits(v1.w);
            } else {
                float4 av = *reinterpret_cast<const float4*>(A + (size_t)(m0 + r_) * K + k0 + c8);
                *reinterpret_cast<float4*>(&As[r_][c8]) = av;
            }
        }
        #pragma unroll
        for (int i = 0; i < 2; i++) {
            int n = (tid >> 2) + i * 128;
            float4 bv = *reinterpret_cast<const float4*>(W + (size_t)n * K + k0 + (tid & 3) * 8);
            *reinterpret_cast<float4*>(&Bs[n][(tid & 3) * 8]) = bv;
        }
        __syncthreads();
        frag8 a = *reinterpret_cast<const frag8*>(&As[lrow][quad * 8]);
        #pragma unroll
        for (int nj = 0; nj < 2; nj++) {
            frag8 b = *reinterpret_cast<const frag8*>(&Bs[w * 32 + nj * 16 + lrow][quad * 8]);
            acc[nj] = __builtin_amdgcn_mfma_f32_16x16x32_bf16(a, b, acc[nj], 0, 0, 0);
        }
        __syncthreads();
    }

    float v[2][4];
    #pragma unroll
    for (int nj = 0; nj < 2; nj++) {
        int col = w * 32 + nj * 16 + lrow;
        #pragma unroll
        for (int r = 0; r < 4; r++) {
            int row = m0 + quad * 4 + r;
            float t = acc[nj][r];
            if (bias) t += bias[col];
            if (res) t += res[(size_t)row * 256 + col];
            v[nj][r] = t;
        }
    }

    if (g1) {
        #pragma unroll
        for (int r = 0; r < 4; r++) {
            float s1 = v[0][r] + v[1][r];
            float s2 = v[0][r]*v[0][r] + v[1][r]*v[1][r];
            s1 = row_sum16(s1); s2 = row_sum16(s2);
            if (lrow == 0) { red[w][quad * 4 + r][0] = s1; red[w][quad * 4 + r][1] = s2; }
        }
        __syncthreads();
        #pragma unroll
        for (int r = 0; r < 4; r++) {
            int rr = quad * 4 + r;
            float t1 = 0.f, t2 = 0.f;
            #pragma unroll
            for (int ww = 0; ww < 8; ww++) { t1 += red[ww][rr][0]; t2 += red[ww][rr][1]; }
            float mu = t1 * (1.0f / 256.0f);
            float var = t2 * (1.0f / 256.0f) - mu * mu;
            float rstd = rsqrtf(var + 1e-5f);
            #pragma unroll
            for (int nj = 0; nj < 2; nj++) {
                int col = w * 32 + nj * 16 + lrow;
                float t = (v[nj][r] - mu) * rstd * g1[col] + b1[col];
                if (gelu1) t = gelu_exact(t);
                v[nj][r] = t;
            }
        }
        __syncthreads();
    } else if (gelu1) {
        #pragma unroll
        for (int nj = 0; nj < 2; nj++)
            #pragma unroll
            for (int r = 0; r < 4; r++)
                v[nj][r] = gelu_exact(v[nj][r]);
    }

    if (outF) {
        #pragma unroll
        for (int nj = 0; nj < 2; nj++) {
            int col = w * 32 + nj * 16 + lrow;
            #pragma unroll
            for (int r = 0; r < 4; r++)
                outF[(size_t)(m0 + quad * 4 + r) * 256 + col] = v[nj][r];
        }
    }

    if (l2out) {
        #pragma unroll
        for (int r = 0; r < 4; r++) {
            float s2 = v[0][r]*v[0][r] + v[1][r]*v[1][r];
            s2 = row_sum16(s2);
            if (lrow == 0) red[w][quad * 4 + r][0] = s2;
        }
        __syncthreads();
        if (tid < 16) {
            float t = 0.f;
            #pragma unroll
            for (int ww = 0; ww < 8; ww++) t += red[ww][tid][0];
            sq[tid] = sqrtf(t);
        }
        __syncthreads();
        if (tid == 0) {
            float a = 0.f;
            #pragma unroll
            for (int i = 0; i < 16; i++) a += sq[i];
            atomicAdd(l2out, a * (0.01f / 4096.0f));
        }
    }

    if (g2) {
        __syncthreads();
        #pragma unroll
        for (int r = 0; r < 4; r++) {
            float s1 = v[0][r] + v[1][r];
            float s2 = v[0][r]*v[0][r] + v[1][r]*v[1][r];
            s1 = row_sum16(s1); s2 = row_sum16(s2);
            if (lrow == 0) { red[w][quad * 4 + r][0] = s1; red[w][quad * 4 + r][1] = s2; }
        }
        __syncthreads();
        #pragma unroll
        for (int r = 0; r < 4; r++) {
            int rr = quad * 4 + r;
            float t1 = 0.f, t2 = 0.f;
            #pragma unroll
            for (int ww = 0; ww < 8; ww++) { t1 += red[ww][rr][0]; t2 += red[ww][rr][1]; }
            float mu = t1 * (1.0f / 256.0f);
            float var = t2 * (1.0f / 256.0f) - mu * mu;
            float rstd = rsqrtf(var + 1e-5f);
            #pragma unroll
            for (int nj = 0; nj < 2; nj++) {
                int col = w * 32 + nj * 16 + lrow;
                outB[(size_t)(m0 + rr) * 256 + col] = bf16bits((v[nj][r] - mu) * rstd * g2[col] + b2[col]);
            }
        }
    } else if (outB) {
        #pragma unroll
        for (int nj = 0; nj < 2; nj++) {
            int col = w * 32 + nj * 16 + lrow;
            #pragma unroll
            for (int r = 0; r < 4; r++)
                outB[(size_t)(m0 + quad * 4 + r) * 256 + col] = bf16bits(v[nj][r]);
        }
    }

    // ---- fused cls GEMM: logits(16 x 128) = v(16 x 256) @ clsW(128 x 256)^T ----
    if (clsW) {
        #pragma unroll
        for (int nj = 0; nj < 2; nj++) {
            int col = w * 32 + nj * 16 + lrow;
            #pragma unroll
            for (int r = 0; r < 4; r++)
                hb[quad * 4 + r][col] = bf16bits(v[nj][r]);
        }
        __syncthreads();
        f32x4 cacc = {};
        #pragma unroll
        for (int k0 = 0; k0 < 256; k0 += 32) {
            frag8 a = *reinterpret_cast<const frag8*>(&hb[lrow][k0 + quad * 8]);
            frag8 b = *reinterpret_cast<const frag8*>(clsW + (size_t)(w * 16 + lrow) * 256 + k0 + quad * 8);
            cacc = __builtin_amdgcn_mfma_f32_16x16x32_bf16(a, b, cacc, 0, 0, 0);
        }
        int col = w * 16 + lrow;
        float cb = clsB[col];
        #pragma unroll
        for (int r = 0; r < 4; r++)
            clsOut[(size_t)(m0 + quad * 4 + r) * 128 + col] = cacc[r] + cb;
    }
}

// ---------------- chunked selective scan (LDS-resident dlt/uc, 1 barrier) -------
__global__ __launch_bounds__(1024)
void scan_chunked(const float* __restrict__ xdt,
                  const float* __restrict__ dtw, const float* __restrict__ dtb,
                  const float* __restrict__ ucT,
                  const float* __restrict__ BT, const float* __restrict__ CT,
                  const unsigned short* __restrict__ szT,
                  const float* __restrict__ Ac,
                  const float* __restrict__ Dp,
                  unsigned short* __restrict__ y)
{
    __shared__ float aprod_s[16][64];
    __shared__ float sfin_s[16][64];
    __shared__ float sin_w[16][64];
    __shared__ __align__(16) float ylocal[16][64][4];
    __shared__ __align__(16) float dltS[4][1032];
    __shared__ __align__(16) float ucS[4][1032];

    const int j = blockIdx.x;
    const int bid = (j & 7) * 64 + (j >> 3);     // XCD swizzle
    const int b = bid >> 7;
    const int d0 = (bid & 127) * 4;
    const int w = threadIdx.x >> 6;
    const int lane = threadIdx.x & 63;
    const int dsub = lane >> 4, s = lane & 15;
    const int d = d0 + dsub;
    const int t = w * 64 + lane;

    const float Acoef = Ac[d * 16 + s];

    // ---- front-end (wave-local): stage uc chunk; compute dlt for own chunk ----
    {
        int dd = lane >> 4, tq = (lane & 15) * 4;
        float4 v = *reinterpret_cast<const float4*>(ucT + ((size_t)(b * 512 + d0 + dd)) * 1024 + w * 64 + tq);
        *reinterpret_cast<float4*>(&ucS[dd][w * 64 + tq]) = v;
    }
    {
        const float* xr = xdt + ((size_t)(b * 1024) + t) * 16;
        float4 x0 = *reinterpret_cast<const float4*>(xr + 0);
        float4 x1 = *reinterpret_cast<const float4*>(xr + 4);
        float4 x2 = *reinterpret_cast<const float4*>(xr + 8);
        float4 x3 = *reinterpret_cast<const float4*>(xr + 12);
        #pragma unroll
        for (int dd = 0; dd < 4; dd++) {
            const float* wt = dtw + (size_t)(d0 + dd) * 16;
            float a2 = dtb[d0 + dd]
                + x0.x * wt[0]  + x0.y * wt[1]  + x0.z * wt[2]  + x0.w * wt[3]
                + x1.x * wt[4]  + x1.y * wt[5]  + x1.z * wt[6]  + x1.w * wt[7]
                + x2.x * wt[8]  + x2.y * wt[9]  + x2.z * wt[10] + x2.w * wt[11]
                + x3.x * wt[12] + x3.y * wt[13] + x3.z * wt[14] + x3.w * wt[15];
            dltS[dd][t] = softplus_f(a2);
        }
    }

    const float4* Bp = reinterpret_cast<const float4*>(BT + ((size_t)(b * 16 + s)) * 1024 + w * 64);
    const float4* Cp = reinterpret_cast<const float4*>(CT + ((size_t)(b * 16 + s)) * 1024 + w * 64);

    // ---- Phase A: local scan (B/C q+1 prefetch; dlt/uc from LDS) ----
    float st = 0.0f, ap = 1.0f;
    float4 B4 = Bp[0], C4 = Cp[0];
    #pragma unroll
    for (int q = 0; q < 16; q++) {
        float4 nB, nC;
        if (q < 15) { nB = Bp[q + 1]; nC = Cp[q + 1]; }
        float4 dt4 = *reinterpret_cast<const float4*>(&dltS[dsub][w * 64 + q * 4]);
        float4 ut4 = *reinterpret_cast<const float4*>(&ucS[dsub][w * 64 + q * 4]);
        const float* dtp = (const float*)&dt4;
        const float* utp = (const float*)&ut4;
        const float* Btp = (const float*)&B4;
        const float* Ctp = (const float*)&C4;
        #pragma unroll
        for (int jj = 0; jj < 4; jj++) {
            float dA = __expf(dtp[jj] * Acoef);
            st = st * dA + dtp[jj] * utp[jj] * Btp[jj];
            ap *= dA;
            float part = row_sum16(st * Ctp[jj]);
            if (s == 0) ylocal[w][q * 4 + jj][dsub] = part;
        }
        B4 = nB; C4 = nC;
    }
    aprod_s[w][lane] = ap;
    sfin_s[w][lane] = st;
    __syncthreads();                                 // the only barrier

    // ---- decentralized combine ----
    {
        float pre = 0.0f;
        #pragma unroll
        for (int c = 0; c < 15; c++) {
            float apc = aprod_s[c][lane];
            float sfc = sfin_s[c][lane];
            float cand = sfc + apc * pre;
            pre = (c < w) ? cand : pre;
        }
        sin_w[w][lane] = pre;
    }

    // ---- Phase C: lane = t; correction via prefix sums + epilogue ----
    float cums[4];
    #pragma unroll
    for (int dd = 0; dd < 4; dd++)
        cums[dd] = dltS[dd][t];
    #pragma unroll
    for (int dd = 0; dd < 4; dd++)
        cums[dd] = prefix_sum64(cums[dd]);

    float4 yl = *reinterpret_cast<const float4*>(&ylocal[w][lane][0]);
    float acc[4] = { yl.x, yl.y, yl.z, yl.w };

    #pragma unroll
    for (int sq = 0; sq < 4; sq++) {
        float Cs[4];
        #pragma unroll
        for (int jj = 0; jj < 4; jj++)
            Cs[jj] = CT[((size_t)(b * 16 + sq * 4 + jj)) * 1024 + t];
        #pragma unroll
        for (int dd = 0; dd < 4; dd++) {
            float4 sin4 = *reinterpret_cast<const float4*>(&sin_w[w][dd * 16 + sq * 4]);
            const float* sp = (const float*)&sin4;
            #pragma unroll
            for (int jj = 0; jj < 4; jj++) {
                float ac = Ac[(d0 + dd) * 16 + sq * 4 + jj];
                acc[dd] += sp[jj] * Cs[jj] * __expf(ac * cums[dd]);
            }
        }
    }

    const size_t row = (size_t)b * 1024 + t;
    #pragma unroll
    for (int dd = 0; dd < 4; dd++) {
        float ut = ucS[dd][t];
        float sz = bf2f(szT[((size_t)(b * 512 + d0 + dd)) * 1024 + t]);
        float yv = acc[dd] + ut * Dp[d0 + dd];
        y[row * 512 + d0 + dd] = bf16bits(yv * sz);
    }
}

// ---------------- launcher ----------------
extern "C" void kernel_launch(void* const* d_in, const int* in_sizes, int n_in,
                              void* d_out, int out_size, void* d_ws, size_t ws_size,
                              hipStream_t stream)
{
    const float* x      = (const float*)d_in[0];
    const float* in_b   = (const float*)d_in[2];
    const float* ln_g   = (const float*)d_in[3];
    const float* ln_b   = (const float*)d_in[4];
    const float* blk_ng  = (const float*)d_in[5];
    const float* blk_nb  = (const float*)d_in[6];
    const float* blk_cw  = (const float*)d_in[8];
    const float* blk_cb  = (const float*)d_in[9];
    const float* blk_dtw = (const float*)d_in[11];
    const float* blk_dtb = (const float*)d_in[12];
    const float* blk_Alog= (const float*)d_in[13];
    const float* blk_D   = (const float*)d_in[14];
    const float* op_b   = (const float*)d_in[17];
    const float* cls_b  = (const float*)d_in[19];
    float* out = (float*)d_out;

    const int BL = 4096;
    float* ws = (float*)d_ws;
    float* h0   = ws;                         // 1,048,576
    float* xzuT = h0 + 1048576;               // 2,097,152  [b][d][t] fp32 (u pre-conv)
    float* ucT  = xzuT + 2097152;             // 2,097,152  [b][d][t]
    float* xdt  = ucT + 2097152;              // 131,072 (2 layers x 4096x16)
    float* BT   = xdt + 131072;               // 131,072 (2 layers x [b][s][t])
    float* CT   = BT + 131072;                // 131,072
    float* Ac   = CT + 131072;                // 16,384
    unsigned short* szT = (unsigned short*)(Ac + 16384);  // 2,097,152 bf16 [b][d][t]
    unsigned short* wb  = szT + 2097152;      // 1,130,496
    unsigned short* hnb = wb + 1130496;       // 1,048,576
    unsigned short* ybb = hnb + 1048576;      // 2,097,152
    unsigned short* h0b = hnb;
    unsigned short* in_wb  = wb;
    unsigned short* ipw_b  = wb + 196608;
    unsigned short* xpw_b  = wb + 720896;
    unsigned short* opw_b  = wb + 770048;
    unsigned short* op_wb  = wb + 1032192;
    unsigned short* cls_wb = wb + 1097728;

    CvtArgs ca;
    ca.src[0] = (const float*)d_in[1];  ca.dst[0] = in_wb;  ca.n4[0] = 196608 / 4;
    ca.src[1] = (const float*)d_in[7];  ca.dst[1] = ipw_b;  ca.n4[1] = 524288 / 4;
    ca.src[2] = (const float*)d_in[10]; ca.dst[2] = xpw_b;  ca.n4[2] = 49152 / 4;
    ca.src[3] = (const float*)d_in[15]; ca.dst[3] = opw_b;  ca.n4[3] = 262144 / 4;
    ca.src[4] = (const float*)d_in[16]; ca.dst[4] = op_wb;  ca.n4[4] = 65536 / 4;
    ca.src[5] = (const float*)d_in[18]; ca.dst[5] = cls_wb; ca.n4[5] = 32768 / 4;
    int total4 = 1130496 / 4;
    int zquads = 393216 / 4;                  // xdt+BT+CT (both layers, contiguous)
    int totalg = total4 + 16384 + zquads;
    cvt_all<<<(totalg + 255) / 256, 256, 0, stream>>>(ca, total4, blk_Alog, Ac,
                                                      xdt, zquads,
                                                      out + (size_t)BL * 128);

    // in_proj (A from fp32 x) + bias + LN + GELU -> h0 (fp32), + LN(layer0) -> hnb
    rowgemm<<<256, 512, 0, stream>>>(nullptr, x, in_wb, in_b, nullptr,
                                     ln_g, ln_b, 1,
                                     blk_ng, blk_nb,
                                     h0, hnb, nullptr,
                                     nullptr, nullptr, nullptr, 768);

    for (int l = 0; l < 2; l++) {
        const float* cw   = blk_cw  + (size_t)l * 512 * 4;
        const float* cb   = blk_cb  + l * 512;
        const float* dtw  = blk_dtw + (size_t)l * 512 * 16;
        const float* dtb  = blk_dtb + l * 512;
        const float* Dl   = blk_D   + l * 512;
        const unsigned short* ipwl = ipw_b + (size_t)l * 262144;
        const unsigned short* xpwl = xpw_b + (size_t)l * 24576;
        const unsigned short* opwl = opw_b + (size_t)l * 131072;
        float* xdtl = xdt + (size_t)l * 65536;
        float* BTl  = BT  + (size_t)l * 65536;
        float* CTl  = CT  + (size_t)l * 65536;

        // ipw GEMM: u -> xzuT fp32 [b][d][t]; z -> silu(z) bf16 szT [b][d][t]
        gemm_ipw<<<dim3(16, 64), 256, 0, stream>>>(hnb, ipwl, xzuT, szT);
        // fused conv + xpw projection (K-split x4): ucT + atomic xdt/BT/CT
        gemm_cat<<<dim3(4, 64), 256, 0, stream>>>(xzuT, xpwl, cw, cb, ucT, xdtl, BTl, CTl);
        // scan (computes dlt from xdt in-kernel) -> ybb
        scan_chunked<<<512, 1024, 0, stream>>>(xdtl, dtw, dtb, ucT, BTl, CTl, szT,
                                               Ac + (size_t)l * 8192, Dl, ybb);
        // h0 += ybb @ opw.T; layer0: +LN(layer1)->hnb; layer1: ->h0b bf16 only
        if (l == 0)
            rowgemm<<<256, 512, 0, stream>>>(ybb, nullptr, opwl, nullptr, h0,
                                             nullptr, nullptr, 0,
                                             blk_ng + 256, blk_nb + 256,
                                             h0, hnb, nullptr,
                                             nullptr, nullptr, nullptr, 512);
        else
            rowgemm<<<256, 512, 0, stream>>>(ybb, nullptr, opwl, nullptr, h0,
                                             nullptr, nullptr, 0,
                                             nullptr, nullptr,
                                             nullptr, h0b, nullptr,
                                             nullptr, nullptr, nullptr, 512);
    }

    // final: h2 = gelu(h0b @ op_w.T + op_b); fused L2 scalar + cls GEMM -> out
    rowgemm<<<256, 512, 0, stream>>>(h0b, nullptr, op_wb, op_b, nullptr,
                                     nullptr, nullptr, 1,
                                     nullptr, nullptr,
                                     nullptr, nullptr, out + (size_t)BL * 128,
                                     cls_wb, cls_b, out, 256);
}

// Round 17
// 302.722 us; speedup vs baseline: 1.2006x; 1.0120x over previous
//
#include <hip/hip_runtime.h>
#include <hip/hip_bf16.h>
#include <math.h>

typedef __attribute__((ext_vector_type(8))) short frag8;   // 8 bf16 (4 VGPRs)
typedef __attribute__((ext_vector_type(4))) float f32x4;

// ---------------- device helpers ----------------
__device__ __forceinline__ float gelu_exact(float x) {
    return 0.5f * x * (1.0f + erff(x * 0.70710678118654752f));
}
__device__ __forceinline__ float softplus_f(float x) {
    return (x > 20.0f) ? x : log1pf(expf(x));
}
__device__ __forceinline__ float sigmoid_f(float x) {
    return 1.0f / (1.0f + __expf(-x));
}
__device__ __forceinline__ unsigned short bf16bits(float x) {
    __hip_bfloat16 h = __float2bfloat16(x);
    return *(unsigned short*)&h;
}
__device__ __forceinline__ float bf2f(unsigned short u) {
    unsigned int v = ((unsigned int)u) << 16;
    return __builtin_bit_cast(float, v);
}
// sum over the 16 lanes of each DPP row-of-16 — VALU-pipe only
__device__ __forceinline__ float row_sum16(float x) {
    int t;
    t = __builtin_amdgcn_update_dpp(0, __builtin_bit_cast(int, x), 0x128, 0xf, 0xf, true); // row_ror:8
    x += __builtin_bit_cast(float, t);
    t = __builtin_amdgcn_update_dpp(0, __builtin_bit_cast(int, x), 0x124, 0xf, 0xf, true); // row_ror:4
    x += __builtin_bit_cast(float, t);
    t = __builtin_amdgcn_update_dpp(0, __builtin_bit_cast(int, x), 0x122, 0xf, 0xf, true); // row_ror:2
    x += __builtin_bit_cast(float, t);
    t = __builtin_amdgcn_update_dpp(0, __builtin_bit_cast(int, x), 0x121, 0xf, 0xf, true); // row_ror:1
    x += __builtin_bit_cast(float, t);
    return x;
}
// inclusive prefix sum over the full 64-lane wave (DPP, VALU-pipe only)
__device__ __forceinline__ float prefix_sum64(float x) {
    int t;
    t = __builtin_amdgcn_update_dpp(0, __builtin_bit_cast(int, x), 0x111, 0xf, 0xf, true); // row_shr:1
    x += __builtin_bit_cast(float, t);
    t = __builtin_amdgcn_update_dpp(0, __builtin_bit_cast(int, x), 0x112, 0xf, 0xf, true); // row_shr:2
    x += __builtin_bit_cast(float, t);
    t = __builtin_amdgcn_update_dpp(0, __builtin_bit_cast(int, x), 0x114, 0xf, 0xf, true); // row_shr:4
    x += __builtin_bit_cast(float, t);
    t = __builtin_amdgcn_update_dpp(0, __builtin_bit_cast(int, x), 0x118, 0xf, 0xf, true); // row_shr:8
    x += __builtin_bit_cast(float, t);
    t = __builtin_amdgcn_update_dpp(0, __builtin_bit_cast(int, x), 0x142, 0xa, 0xf, true); // row_bcast:15
    x += __builtin_bit_cast(float, t);
    t = __builtin_amdgcn_update_dpp(0, __builtin_bit_cast(int, x), 0x143, 0xc, 0xf, true); // row_bcast:31
    x += __builtin_bit_cast(float, t);
    return x;
}

// -------- fp32->bf16 weight cvt + Acoef + l2 zero + zero xdt/BT/CT (both layers)
struct CvtArgs {
    const float* src[6];
    unsigned short* dst[6];
    int n4[6];
};
__global__ __launch_bounds__(256)
void cvt_all(CvtArgs a, int total4, const float* __restrict__ Alog,
             float* __restrict__ Ac, float* __restrict__ Z, int zquads, float* l2)
{
    int i = blockIdx.x * 256 + threadIdx.x;
    if (i >= total4) {
        int j = i - total4;
        if (j < 16384) {
            Ac[j] = -__expf(Alog[j]);
        } else {
            int z = j - 16384;
            if (z < zquads) {
                float4 zero = {0.f, 0.f, 0.f, 0.f};
                reinterpret_cast<float4*>(Z)[z] = zero;
            }
        }
        if (j == 0) *l2 = 0.0f;
        return;
    }
    int seg = 0;
    while (i >= a.n4[seg]) { i -= a.n4[seg]; seg++; }
    float4 v = reinterpret_cast<const float4*>(a.src[seg])[i];
    ushort4 o;
    o.x = bf16bits(v.x); o.y = bf16bits(v.y); o.z = bf16bits(v.z); o.w = bf16bits(v.w);
    reinterpret_cast<ushort4*>(a.dst[seg])[i] = o;
}

// ---------------- ipw GEMM (N=1024, K=256): u-half -> xzuT fp32 [b][d][t],
// ---------------- z-half -> silu(z) bf16 szT [b][d][t] ----------------
__global__ __launch_bounds__(256)
void gemm_ipw(const unsigned short* __restrict__ A,
              const unsigned short* __restrict__ W,
              float* __restrict__ xzuT,
              unsigned short* __restrict__ szT)
{
    __shared__ __align__(16) unsigned short As[64][40];
    __shared__ __align__(16) unsigned short Bs[64][40];

    const int tid = threadIdx.x;
    const int wid = tid >> 6, lane = tid & 63;
    const int wm = (wid >> 1) * 32, wn = (wid & 1) * 32;
    const int m0 = blockIdx.y * 64, n0 = blockIdx.x * 64;
    const int lrow = lane & 15, quad = lane >> 4;
    const int K = 256;

    const int sm = tid >> 2;
    const int sk = (tid & 3) * 8;

    f32x4 acc[2][2] = {};

    for (int k0 = 0; k0 < K; k0 += 32) {
        float4 av = *reinterpret_cast<const float4*>(A + (size_t)(m0 + sm) * K + k0 + sk);
        *reinterpret_cast<float4*>(&As[sm][sk]) = av;
        float4 bv = *reinterpret_cast<const float4*>(W + (size_t)(n0 + sm) * K + k0 + sk);
        *reinterpret_cast<float4*>(&Bs[sm][sk]) = bv;
        __syncthreads();

        frag8 a0 = *reinterpret_cast<const frag8*>(&As[wm + lrow][quad * 8]);
        frag8 a1 = *reinterpret_cast<const frag8*>(&As[wm + 16 + lrow][quad * 8]);
        frag8 b0 = *reinterpret_cast<const frag8*>(&Bs[wn + lrow][quad * 8]);
        frag8 b1 = *reinterpret_cast<const frag8*>(&Bs[wn + 16 + lrow][quad * 8]);

        acc[0][0] = __builtin_amdgcn_mfma_f32_16x16x32_bf16(a0, b0, acc[0][0], 0, 0, 0);
        acc[0][1] = __builtin_amdgcn_mfma_f32_16x16x32_bf16(a0, b1, acc[0][1], 0, 0, 0);
        acc[1][0] = __builtin_amdgcn_mfma_f32_16x16x32_bf16(a1, b0, acc[1][0], 0, 0, 0);
        acc[1][1] = __builtin_amdgcn_mfma_f32_16x16x32_bf16(a1, b1, acc[1][1], 0, 0, 0);
        __syncthreads();
    }

    const int bb = m0 >> 10;
    const int tb = m0 & 1023;
    #pragma unroll
    for (int mi = 0; mi < 2; mi++) {
        int t4 = tb + wm + mi * 16 + quad * 4;
        #pragma unroll
        for (int nj = 0; nj < 2; nj++) {
            int col = n0 + wn + nj * 16 + lrow;
            if (col < 512) {
                float4 o = { acc[mi][nj][0], acc[mi][nj][1], acc[mi][nj][2], acc[mi][nj][3] };
                *reinterpret_cast<float4*>(xzuT + ((size_t)(bb * 512 + col)) * 1024 + t4) = o;
            } else {
                int z = col - 512;
                ushort4 o;
                float v0 = acc[mi][nj][0], v1 = acc[mi][nj][1], v2 = acc[mi][nj][2], v3 = acc[mi][nj][3];
                o.x = bf16bits(v0 * sigmoid_f(v0));
                o.y = bf16bits(v1 * sigmoid_f(v1));
                o.z = bf16bits(v2 * sigmoid_f(v2));
                o.w = bf16bits(v3 * sigmoid_f(v3));
                *reinterpret_cast<ushort4*>(szT + ((size_t)(bb * 512 + z)) * 1024 + t4) = o;
            }
        }
    }
}

// ---------------- conv4+SiLU fused into xpw projection, K-split x4 --------------
// outputs via atomicAdd into zero-initialized xdt (row-major dt), BT, CT (transposed)
__global__ __launch_bounds__(256)
void gemm_cat(const float* __restrict__ xzuT,
              const unsigned short* __restrict__ W,     // xpw: 48 x 512 bf16
              const float* __restrict__ cw, const float* __restrict__ cb,
              float* __restrict__ ucT,
              float* __restrict__ xdt, float* __restrict__ BT, float* __restrict__ CT)
{
    __shared__ __align__(16) unsigned short As[64][40];
    __shared__ __align__(16) unsigned short Bs[64][40];

    const int tid = threadIdx.x;
    const int wid = tid >> 6, lane = tid & 63;
    const int wm = (wid >> 1) * 32, wn = (wid & 1) * 32;
    const int kc = blockIdx.x;            // 0..3 (128-d chunk)
    const int m0 = blockIdx.y * 64;
    const int bb = m0 >> 10;
    const int tb = m0 & 1023;
    const int lrow = lane & 15, quad = lane >> 4;
    const int N = 48;

    const int sm = tid >> 2;
    const int sk = (tid & 3) * 8;

    f32x4 acc[2][2] = {};

    for (int k0 = 0; k0 < 128; k0 += 32) {
        #pragma unroll
        for (int p = 0; p < 2; p++) {
            int kk = (tid >> 4) + p * 16;
            int k  = kc * 128 + k0 + kk;
            int mq = tid & 15;
            int tg = tb + mq * 4;
            const float* rowp = xzuT + ((size_t)(bb * 512 + k)) * 1024;
            float4 cur = *reinterpret_cast<const float4*>(rowp + tg);
            float4 prev = {0.f, 0.f, 0.f, 0.f};
            if (tg != 0) prev = *reinterpret_cast<const float4*>(rowp + tg - 4);
            float4 cv = *reinterpret_cast<const float4*>(cw + k * 4);
            float cbv = cb[k];
            float o0 = cbv + cv.x*prev.y + cv.y*prev.z + cv.z*prev.w + cv.w*cur.x;
            float o1 = cbv + cv.x*prev.z + cv.y*prev.w + cv.z*cur.x  + cv.w*cur.y;
            float o2 = cbv + cv.x*prev.w + cv.y*cur.x  + cv.z*cur.y  + cv.w*cur.z;
            float o3 = cbv + cv.x*cur.x  + cv.y*cur.y  + cv.z*cur.z  + cv.w*cur.w;
            o0 *= sigmoid_f(o0); o1 *= sigmoid_f(o1);
            o2 *= sigmoid_f(o2); o3 *= sigmoid_f(o3);
            float4 uo = { o0, o1, o2, o3 };
            *reinterpret_cast<float4*>(ucT + ((size_t)(bb * 512 + k)) * 1024 + tg) = uo;
            As[mq * 4 + 0][kk] = bf16bits(o0);
            As[mq * 4 + 1][kk] = bf16bits(o1);
            As[mq * 4 + 2][kk] = bf16bits(o2);
            As[mq * 4 + 3][kk] = bf16bits(o3);
        }
        float4 bv = {0.f, 0.f, 0.f, 0.f};
        if (sm < N) bv = *reinterpret_cast<const float4*>(W + (size_t)sm * 512 + kc * 128 + k0 + sk);
        *reinterpret_cast<float4*>(&Bs[sm][sk]) = bv;
        __syncthreads();

        frag8 a0 = *reinterpret_cast<const frag8*>(&As[wm + lrow][quad * 8]);
        frag8 a1 = *reinterpret_cast<const frag8*>(&As[wm + 16 + lrow][quad * 8]);
        frag8 b0 = *reinterpret_cast<const frag8*>(&Bs[wn + lrow][quad * 8]);
        frag8 b1 = *reinterpret_cast<const frag8*>(&Bs[wn + 16 + lrow][quad * 8]);

        acc[0][0] = __builtin_amdgcn_mfma_f32_16x16x32_bf16(a0, b0, acc[0][0], 0, 0, 0);
        acc[0][1] = __builtin_amdgcn_mfma_f32_16x16x32_bf16(a0, b1, acc[0][1], 0, 0, 0);
        acc[1][0] = __builtin_amdgcn_mfma_f32_16x16x32_bf16(a1, b0, acc[1][0], 0, 0, 0);
        acc[1][1] = __builtin_amdgcn_mfma_f32_16x16x32_bf16(a1, b1, acc[1][1], 0, 0, 0);
        __syncthreads();
    }

    #pragma unroll
    for (int mi = 0; mi < 2; mi++) {
        #pragma unroll
        for (int nj = 0; nj < 2; nj++) {
            int col = wn + nj * 16 + lrow;
            if (col >= N) continue;
            #pragma unroll
            for (int r = 0; r < 4; r++) {
                int trow = tb + wm + mi * 16 + quad * 4 + r;     // t within batch
                float v = acc[mi][nj][r];
                if (col < 16)
                    atomicAdd(&xdt[((size_t)(bb * 1024 + trow)) * 16 + col], v);
                else if (col < 32)
                    atomicAdd(&BT[((size_t)(bb * 16 + col - 16)) * 1024 + trow], v);
                else
                    atomicAdd(&CT[((size_t)(bb * 16 + col - 32)) * 1024 + trow], v);
            }
        }
    }
}

// ---------------- full-row GEMM (N=256), 512 threads / 8 waves ------------------
__global__ __launch_bounds__(512)
void rowgemm(const unsigned short* __restrict__ A,
             const float* __restrict__ Af,
             const unsigned short* __restrict__ W,
             const float* __restrict__ bias,
             const float* res,
             const float* g1, const float* b1, int gelu1,
             const float* g2, const float* b2,
             float* outF, unsigned short* outB, float* l2out,
             const unsigned short* clsW, const float* clsB, float* clsOut,
             int K)
{
    __shared__ __align__(16) unsigned short As[16][40];
    __shared__ __align__(16) unsigned short Bs[256][40];
    __shared__ float red[8][16][2];
    __shared__ float sq[16];
    __shared__ __align__(16) unsigned short hb[16][264];

    const int tid = threadIdx.x;
    const int w = tid >> 6, lane = tid & 63;
    const int lrow = lane & 15, quad = lane >> 4;
    const int m0 = blockIdx.x * 16;

    f32x4 acc[2] = {};

    for (int k0 = 0; k0 < K; k0 += 32) {
        if (tid < 64) {
            int r_ = tid >> 2, c8 = (tid & 3) * 8;
            if (Af) {
                float4 v0 = *reinterpret_cast<const float4*>(Af + (size_t)(m0 + r_) * K + k0 + c8);
                float4 v1 = *reinterpret_cast<const float4*>(Af + (size_t)(m0 + r_) * K + k0 + c8 + 4);
                unsigned short* dst = &As[r_][c8];
                dst[0] = bf16bits(v0.x); dst[1] = bf16bits(v0.y);
                dst[2] = bf16bits(v0.z); dst[3] = bf16bits(v0.w);
                dst[4] = bf16bits(v1.x); dst[5] = bf16bits(v1.y);
                dst[6] = bf16bits(v1.z); dst[7] = bf16bits(v1.w);
            } else {
                float4 av = *reinterpret_cast<const float4*>(A + (size_t)(m0 + r_) * K + k0 + c8);
                *reinterpret_cast<float4*>(&As[r_][c8]) = av;
            }
        }
        #pragma unroll
        for (int i = 0; i < 2; i++) {
            int n = (tid >> 2) + i * 128;
            float4 bv = *reinterpret_cast<const float4*>(W + (size_t)n * K + k0 + (tid & 3) * 8);
            *reinterpret_cast<float4*>(&Bs[n][(tid & 3) * 8]) = bv;
        }
        __syncthreads();
        frag8 a = *reinterpret_cast<const frag8*>(&As[lrow][quad * 8]);
        #pragma unroll
        for (int nj = 0; nj < 2; nj++) {
            frag8 b = *reinterpret_cast<const frag8*>(&Bs[w * 32 + nj * 16 + lrow][quad * 8]);
            acc[nj] = __builtin_amdgcn_mfma_f32_16x16x32_bf16(a, b, acc[nj], 0, 0, 0);
        }
        __syncthreads();
    }

    float v[2][4];
    #pragma unroll
    for (int nj = 0; nj < 2; nj++) {
        int col = w * 32 + nj * 16 + lrow;
        #pragma unroll
        for (int r = 0; r < 4; r++) {
            int row = m0 + quad * 4 + r;
            float t = acc[nj][r];
            if (bias) t += bias[col];
            if (res) t += res[(size_t)row * 256 + col];
            v[nj][r] = t;
        }
    }

    if (g1) {
        #pragma unroll
        for (int r = 0; r < 4; r++) {
            float s1 = v[0][r] + v[1][r];
            float s2 = v[0][r]*v[0][r] + v[1][r]*v[1][r];
            s1 = row_sum16(s1); s2 = row_sum16(s2);
            if (lrow == 0) { red[w][quad * 4 + r][0] = s1; red[w][quad * 4 + r][1] = s2; }
        }
        __syncthreads();
        #pragma unroll
        for (int r = 0; r < 4; r++) {
            int rr = quad * 4 + r;
            float t1 = 0.f, t2 = 0.f;
            #pragma unroll
            for (int ww = 0; ww < 8; ww++) { t1 += red[ww][rr][0]; t2 += red[ww][rr][1]; }
            float mu = t1 * (1.0f / 256.0f);
            float var = t2 * (1.0f / 256.0f) - mu * mu;
            float rstd = rsqrtf(var + 1e-5f);
            #pragma unroll
            for (int nj = 0; nj < 2; nj++) {
                int col = w * 32 + nj * 16 + lrow;
                float t = (v[nj][r] - mu) * rstd * g1[col] + b1[col];
                if (gelu1) t = gelu_exact(t);
                v[nj][r] = t;
            }
        }
        __syncthreads();
    } else if (gelu1) {
        #pragma unroll
        for (int nj = 0; nj < 2; nj++)
            #pragma unroll
            for (int r = 0; r < 4; r++)
                v[nj][r] = gelu_exact(v[nj][r]);
    }

    if (outF) {
        #pragma unroll
        for (int nj = 0; nj < 2; nj++) {
            int col = w * 32 + nj * 16 + lrow;
            #pragma unroll
            for (int r = 0; r < 4; r++)
                outF[(size_t)(m0 + quad * 4 + r) * 256 + col] = v[nj][r];
        }
    }

    if (l2out) {
        #pragma unroll
        for (int r = 0; r < 4; r++) {
            float s2 = v[0][r]*v[0][r] + v[1][r]*v[1][r];
            s2 = row_sum16(s2);
            if (lrow == 0) red[w][quad * 4 + r][0] = s2;
        }
        __syncthreads();
        if (tid < 16) {
            float t = 0.f;
            #pragma unroll
            for (int ww = 0; ww < 8; ww++) t += red[ww][tid][0];
            sq[tid] = sqrtf(t);
        }
        __syncthreads();
        if (tid == 0) {
            float a = 0.f;
            #pragma unroll
            for (int i = 0; i < 16; i++) a += sq[i];
            atomicAdd(l2out, a * (0.01f / 4096.0f));
        }
    }

    if (g2) {
        __syncthreads();
        #pragma unroll
        for (int r = 0; r < 4; r++) {
            float s1 = v[0][r] + v[1][r];
            float s2 = v[0][r]*v[0][r] + v[1][r]*v[1][r];
            s1 = row_sum16(s1); s2 = row_sum16(s2);
            if (lrow == 0) { red[w][quad * 4 + r][0] = s1; red[w][quad * 4 + r][1] = s2; }
        }
        __syncthreads();
        #pragma unroll
        for (int r = 0; r < 4; r++) {
            int rr = quad * 4 + r;
            float t1 = 0.f, t2 = 0.f;
            #pragma unroll
            for (int ww = 0; ww < 8; ww++) { t1 += red[ww][rr][0]; t2 += red[ww][rr][1]; }
            float mu = t1 * (1.0f / 256.0f);
            float var = t2 * (1.0f / 256.0f) - mu * mu;
            float rstd = rsqrtf(var + 1e-5f);
            #pragma unroll
            for (int nj = 0; nj < 2; nj++) {
                int col = w * 32 + nj * 16 + lrow;
                outB[(size_t)(m0 + rr) * 256 + col] = bf16bits((v[nj][r] - mu) * rstd * g2[col] + b2[col]);
            }
        }
    } else if (outB) {
        #pragma unroll
        for (int nj = 0; nj < 2; nj++) {
            int col = w * 32 + nj * 16 + lrow;
            #pragma unroll
            for (int r = 0; r < 4; r++)
                outB[(size_t)(m0 + quad * 4 + r) * 256 + col] = bf16bits(v[nj][r]);
        }
    }

    // ---- fused cls GEMM: logits(16 x 128) = v(16 x 256) @ clsW(128 x 256)^T ----
    if (clsW) {
        #pragma unroll
        for (int nj = 0; nj < 2; nj++) {
            int col = w * 32 + nj * 16 + lrow;
            #pragma unroll
            for (int r = 0; r < 4; r++)
                hb[quad * 4 + r][col] = bf16bits(v[nj][r]);
        }
        __syncthreads();
        f32x4 cacc = {};
        #pragma unroll
        for (int k0 = 0; k0 < 256; k0 += 32) {
            frag8 a = *reinterpret_cast<const frag8*>(&hb[lrow][k0 + quad * 8]);
            frag8 b = *reinterpret_cast<const frag8*>(clsW + (size_t)(w * 16 + lrow) * 256 + k0 + quad * 8);
            cacc = __builtin_amdgcn_mfma_f32_16x16x32_bf16(a, b, cacc, 0, 0, 0);
        }
        int col = w * 16 + lrow;
        float cb = clsB[col];
        #pragma unroll
        for (int r = 0; r < 4; r++)
            clsOut[(size_t)(m0 + quad * 4 + r) * 128 + col] = cacc[r] + cb;
    }
}

// ---------------- chunked selective scan (LDS-resident dlt/uc, 1 barrier) -------
__global__ __launch_bounds__(1024)
void scan_chunked(const float* __restrict__ xdt,
                  const float* __restrict__ dtw, const float* __restrict__ dtb,
                  const float* __restrict__ ucT,
                  const float* __restrict__ BT, const float* __restrict__ CT,
                  const unsigned short* __restrict__ szT,
                  const float* __restrict__ Ac,
                  const float* __restrict__ Dp,
                  unsigned short* __restrict__ y)
{
    __shared__ float aprod_s[16][64];
    __shared__ float sfin_s[16][64];
    __shared__ float sin_w[16][64];
    __shared__ __align__(16) float ylocal[16][64][4];
    __shared__ __align__(16) float dltS[4][1032];
    __shared__ __align__(16) float ucS[4][1032];

    const int j = blockIdx.x;
    const int bid = (j & 7) * 64 + (j >> 3);     // XCD swizzle
    const int b = bid >> 7;
    const int d0 = (bid & 127) * 4;
    const int w = threadIdx.x >> 6;
    const int lane = threadIdx.x & 63;
    const int dsub = lane >> 4, s = lane & 15;
    const int d = d0 + dsub;
    const int t = w * 64 + lane;

    const float Acoef = Ac[d * 16 + s];

    const float4* Bp = reinterpret_cast<const float4*>(BT + ((size_t)(b * 16 + s)) * 1024 + w * 64);
    const float4* Cp = reinterpret_cast<const float4*>(CT + ((size_t)(b * 16 + s)) * 1024 + w * 64);

    // ---- issue long-latency loads first: uc stage, xdt, B/C tile 0, sz ----
    {
        int dd = lane >> 4, tq = (lane & 15) * 4;
        float4 v = *reinterpret_cast<const float4*>(ucT + ((size_t)(b * 512 + d0 + dd)) * 1024 + w * 64 + tq);
        *reinterpret_cast<float4*>(&ucS[dd][w * 64 + tq]) = v;
    }
    const float* xr = xdt + ((size_t)(b * 1024) + t) * 16;
    float4 x0 = *reinterpret_cast<const float4*>(xr + 0);
    float4 x1 = *reinterpret_cast<const float4*>(xr + 4);
    float4 x2 = *reinterpret_cast<const float4*>(xr + 8);
    float4 x3 = *reinterpret_cast<const float4*>(xr + 12);
    float4 B4 = Bp[0], C4 = Cp[0];
    unsigned short szr[4];
    #pragma unroll
    for (int dd = 0; dd < 4; dd++)
        szr[dd] = szT[((size_t)(b * 512 + d0 + dd)) * 1024 + t];

    // ---- front-end: compute dlt for own chunk (lane = t) ----
    #pragma unroll
    for (int dd = 0; dd < 4; dd++) {
        const float* wt = dtw + (size_t)(d0 + dd) * 16;
        float a2 = dtb[d0 + dd]
            + x0.x * wt[0]  + x0.y * wt[1]  + x0.z * wt[2]  + x0.w * wt[3]
            + x1.x * wt[4]  + x1.y * wt[5]  + x1.z * wt[6]  + x1.w * wt[7]
            + x2.x * wt[8]  + x2.y * wt[9]  + x2.z * wt[10] + x2.w * wt[11]
            + x3.x * wt[12] + x3.y * wt[13] + x3.z * wt[14] + x3.w * wt[15];
        dltS[dd][t] = softplus_f(a2);
    }

    // ---- Phase A: local scan (B/C q+1 prefetch; dlt/uc from LDS) ----
    float st = 0.0f, ap = 1.0f;
    #pragma unroll
    for (int q = 0; q < 16; q++) {
        float4 nB, nC;
        if (q < 15) { nB = Bp[q + 1]; nC = Cp[q + 1]; }
        float4 dt4 = *reinterpret_cast<const float4*>(&dltS[dsub][w * 64 + q * 4]);
        float4 ut4 = *reinterpret_cast<const float4*>(&ucS[dsub][w * 64 + q * 4]);
        const float* dtp = (const float*)&dt4;
        const float* utp = (const float*)&ut4;
        const float* Btp = (const float*)&B4;
        const float* Ctp = (const float*)&C4;
        #pragma unroll
        for (int jj = 0; jj < 4; jj++) {
            float dA = __expf(dtp[jj] * Acoef);
            st = st * dA + dtp[jj] * utp[jj] * Btp[jj];
            ap *= dA;
            float part = row_sum16(st * Ctp[jj]);
            if (s == 0) ylocal[w][q * 4 + jj][dsub] = part;
        }
        B4 = nB; C4 = nC;
    }
    aprod_s[w][lane] = ap;
    sfin_s[w][lane] = st;
    __syncthreads();                                 // the only barrier

    // ---- decentralized combine ----
    {
        float pre = 0.0f;
        #pragma unroll
        for (int c = 0; c < 15; c++) {
            float apc = aprod_s[c][lane];
            float sfc = sfin_s[c][lane];
            float cand = sfc + apc * pre;
            pre = (c < w) ? cand : pre;
        }
        sin_w[w][lane] = pre;
    }

    // ---- Phase C: lane = t; correction via prefix sums + epilogue ----
    float cums[4];
    #pragma unroll
    for (int dd = 0; dd < 4; dd++)
        cums[dd] = dltS[dd][t];
    #pragma unroll
    for (int dd = 0; dd < 4; dd++)
        cums[dd] = prefix_sum64(cums[dd]);

    float4 yl = *reinterpret_cast<const float4*>(&ylocal[w][lane][0]);
    float acc[4] = { yl.x, yl.y, yl.z, yl.w };

    float Cs[4];
    #pragma unroll
    for (int jj = 0; jj < 4; jj++)
        Cs[jj] = CT[((size_t)(b * 16 + jj)) * 1024 + t];
    #pragma unroll
    for (int sq = 0; sq < 4; sq++) {
        float Csn[4];
        if (sq < 3) {
            #pragma unroll
            for (int jj = 0; jj < 4; jj++)
                Csn[jj] = CT[((size_t)(b * 16 + (sq + 1) * 4 + jj)) * 1024 + t];
        }
        #pragma unroll
        for (int dd = 0; dd < 4; dd++) {
            float4 sin4 = *reinterpret_cast<const float4*>(&sin_w[w][dd * 16 + sq * 4]);
            const float* sp = (const float*)&sin4;
            #pragma unroll
            for (int jj = 0; jj < 4; jj++) {
                float ac = Ac[(d0 + dd) * 16 + sq * 4 + jj];
                acc[dd] += sp[jj] * Cs[jj] * __expf(ac * cums[dd]);
            }
        }
        #pragma unroll
        for (int jj = 0; jj < 4; jj++) Cs[jj] = Csn[jj];
    }

    const size_t row = (size_t)b * 1024 + t;
    ushort4 yo;
    {
        float ut0 = ucS[0][t], ut1 = ucS[1][t], ut2 = ucS[2][t], ut3 = ucS[3][t];
        float y0 = (acc[0] + ut0 * Dp[d0 + 0]) * bf2f(szr[0]);
        float y1 = (acc[1] + ut1 * Dp[d0 + 1]) * bf2f(szr[1]);
        float y2 = (acc[2] + ut2 * Dp[d0 + 2]) * bf2f(szr[2]);
        float y3 = (acc[3] + ut3 * Dp[d0 + 3]) * bf2f(szr[3]);
        yo.x = bf16bits(y0); yo.y = bf16bits(y1);
        yo.z = bf16bits(y2); yo.w = bf16bits(y3);
    }
    *reinterpret_cast<ushort4*>(y + row * 512 + d0) = yo;
}

// ---------------- launcher ----------------
extern "C" void kernel_launch(void* const* d_in, const int* in_sizes, int n_in,
                              void* d_out, int out_size, void* d_ws, size_t ws_size,
                              hipStream_t stream)
{
    const float* x      = (const float*)d_in[0];
    const float* in_b   = (const float*)d_in[2];
    const float* ln_g   = (const float*)d_in[3];
    const float* ln_b   = (const float*)d_in[4];
    const float* blk_ng  = (const float*)d_in[5];
    const float* blk_nb  = (const float*)d_in[6];
    const float* blk_cw  = (const float*)d_in[8];
    const float* blk_cb  = (const float*)d_in[9];
    const float* blk_dtw = (const float*)d_in[11];
    const float* blk_dtb = (const float*)d_in[12];
    const float* blk_Alog= (const float*)d_in[13];
    const float* blk_D   = (const float*)d_in[14];
    const float* op_b   = (const float*)d_in[17];
    const float* cls_b  = (const float*)d_in[19];
    float* out = (float*)d_out;

    const int BL = 4096;
    float* ws = (float*)d_ws;
    float* h0   = ws;                         // 1,048,576
    float* xzuT = h0 + 1048576;               // 2,097,152  [b][d][t] fp32 (u pre-conv)
    float* ucT  = xzuT + 2097152;             // 2,097,152  [b][d][t]
    float* xdt  = ucT + 2097152;              // 131,072 (2 layers x 4096x16)
    float* BT   = xdt + 131072;               // 131,072 (2 layers x [b][s][t])
    float* CT   = BT + 131072;                // 131,072
    float* Ac   = CT + 131072;                // 16,384
    unsigned short* szT = (unsigned short*)(Ac + 16384);  // 2,097,152 bf16 [b][d][t]
    unsigned short* wb  = szT + 2097152;      // 1,130,496
    unsigned short* hnb = wb + 1130496;       // 1,048,576
    unsigned short* ybb = hnb + 1048576;      // 2,097,152
    unsigned short* h0b = hnb;
    unsigned short* in_wb  = wb;
    unsigned short* ipw_b  = wb + 196608;
    unsigned short* xpw_b  = wb + 720896;
    unsigned short* opw_b  = wb + 770048;
    unsigned short* op_wb  = wb + 1032192;
    unsigned short* cls_wb = wb + 1097728;

    CvtArgs ca;
    ca.src[0] = (const float*)d_in[1];  ca.dst[0] = in_wb;  ca.n4[0] = 196608 / 4;
    ca.src[1] = (const float*)d_in[7];  ca.dst[1] = ipw_b;  ca.n4[1] = 524288 / 4;
    ca.src[2] = (const float*)d_in[10]; ca.dst[2] = xpw_b;  ca.n4[2] = 49152 / 4;
    ca.src[3] = (const float*)d_in[15]; ca.dst[3] = opw_b;  ca.n4[3] = 262144 / 4;
    ca.src[4] = (const float*)d_in[16]; ca.dst[4] = op_wb;  ca.n4[4] = 65536 / 4;
    ca.src[5] = (const float*)d_in[18]; ca.dst[5] = cls_wb; ca.n4[5] = 32768 / 4;
    int total4 = 1130496 / 4;
    int zquads = 393216 / 4;                  // xdt+BT+CT (both layers, contiguous)
    int totalg = total4 + 16384 + zquads;
    cvt_all<<<(totalg + 255) / 256, 256, 0, stream>>>(ca, total4, blk_Alog, Ac,
                                                      xdt, zquads,
                                                      out + (size_t)BL * 128);

    // in_proj (A from fp32 x) + bias + LN + GELU -> h0 (fp32), + LN(layer0) -> hnb
    rowgemm<<<256, 512, 0, stream>>>(nullptr, x, in_wb, in_b, nullptr,
                                     ln_g, ln_b, 1,
                                     blk_ng, blk_nb,
                                     h0, hnb, nullptr,
                                     nullptr, nullptr, nullptr, 768);

    for (int l = 0; l < 2; l++) {
        const float* cw   = blk_cw  + (size_t)l * 512 * 4;
        const float* cb   = blk_cb  + l * 512;
        const float* dtw  = blk_dtw + (size_t)l * 512 * 16;
        const float* dtb  = blk_dtb + l * 512;
        const float* Dl   = blk_D   + l * 512;
        const unsigned short* ipwl = ipw_b + (size_t)l * 262144;
        const unsigned short* xpwl = xpw_b + (size_t)l * 24576;
        const unsigned short* opwl = opw_b + (size_t)l * 131072;
        float* xdtl = xdt + (size_t)l * 65536;
        float* BTl  = BT  + (size_t)l * 65536;
        float* CTl  = CT  + (size_t)l * 65536;

        // ipw GEMM: u -> xzuT fp32 [b][d][t]; z -> silu(z) bf16 szT [b][d][t]
        gemm_ipw<<<dim3(16, 64), 256, 0, stream>>>(hnb, ipwl, xzuT, szT);
        // fused conv + xpw projection (K-split x4): ucT + atomic xdt/BT/CT
        gemm_cat<<<dim3(4, 64), 256, 0, stream>>>(xzuT, xpwl, cw, cb, ucT, xdtl, BTl, CTl);
        // scan (computes dlt from xdt in-kernel) -> ybb
        scan_chunked<<<512, 1024, 0, stream>>>(xdtl, dtw, dtb, ucT, BTl, CTl, szT,
                                               Ac + (size_t)l * 8192, Dl, ybb);
        // h0 += ybb @ opw.T; layer0: +LN(layer1)->hnb; layer1: ->h0b bf16 only
        if (l == 0)
            rowgemm<<<256, 512, 0, stream>>>(ybb, nullptr, opwl, nullptr, h0,
                                             nullptr, nullptr, 0,
                                             blk_ng + 256, blk_nb + 256,
                                             h0, hnb, nullptr,
                                             nullptr, nullptr, nullptr, 512);
        else
            rowgemm<<<256, 512, 0, stream>>>(ybb, nullptr, opwl, nullptr, h0,
                                             nullptr, nullptr, 0,
                                             nullptr, nullptr,
                                             nullptr, h0b, nullptr,
                                             nullptr, nullptr, nullptr, 512);
    }

    // final: h2 = gelu(h0b @ op_w.T + op_b); fused L2 scalar + cls GEMM -> out
    rowgemm<<<256, 512, 0, stream>>>(h0b, nullptr, op_wb, op_b, nullptr,
                                     nullptr, nullptr, 1,
                                     nullptr, nullptr,
                                     nullptr, nullptr, out + (size_t)BL * 128,
                                     cls_wb, cls_b, out, 256);
}